// Round 1
// baseline (156.891 us; speedup 1.0000x reference)
//
#include <hip/hip_runtime.h>

typedef unsigned short u16;
typedef unsigned int   u32;

using bf16x8 = __attribute__((ext_vector_type(8))) short;
using f32x4  = __attribute__((ext_vector_type(4))) float;

__device__ __forceinline__ u16 f2bf(float f) {
  u32 u = __float_as_uint(f);
  u32 r = u + 0x7FFFu + ((u >> 16) & 1u);   // round-to-nearest-even
  return (u16)(r >> 16);
}

// ---------------------------------------------------------------------------
// SRNN kernel: one WG per (t, d, b-block of 8). 62-step scan, history h-rows
// live in an LDS slot pool (static liveness schedule computed on host).
// Per step: acc = mfma(x, Uw) + sum_{nb<=3} sum_{kc<4} mfma(h_slot, W).
// ---------------------------------------------------------------------------
#define NSLOT 18
#define SLOT_BYTES (8 * 272)                 // [8 rows][136 bf16] (+8 pad cols)
#define POOL_BYTES (NSLOT * SLOT_BYTES)      // 39168
#define X_OFF      POOL_BYTES
#define X_BYTES    (63 * 16 * 8 * 2)         // 16128  [pi(+1 pad)][16 b][8 c] bf16
#define UW_OFF     (X_OFF + X_BYTES)         // 55296
#define UW_BYTES   (132 * 8 * 2)             // 2112   [n(+4 pad)][8 c] bf16
#define WP_OFF     (UW_OFF + UW_BYTES)       // 57408  wproj[62] f32
#define SC_OFF     (WP_OFF + 256)            // 57664  packed sched[62] u32
#define SMEM_BYTES (SC_OFF + 256)            // 57920 (< 64 KiB static)

__global__ __launch_bounds__(256) void srnn_kernel(
    const float* __restrict__ x,    const float* __restrict__ Uw,
    const float* __restrict__ Ub,   const float* __restrict__ Ww,
    const float* __restrict__ Wb,   const float* __restrict__ spbs,
    const float* __restrict__ Pw,   const float* __restrict__ psw,
    const unsigned* __restrict__ sched, float* __restrict__ part)
{
  __shared__ __align__(16) char smem[SMEM_BYTES];
  const int tid  = threadIdx.x;
  const int lane = tid & 63, wid = tid >> 6;
  const int l15  = lane & 15, lhi = lane >> 4;
  const int bx = blockIdx.x;
  const int bb = bx & 15, d = (bx >> 4) & 3, t = bx >> 6;
  const int b0 = bb * 8;

  unsigned* s_sc = (unsigned*)(smem + SC_OFF);
  float*    s_wp = (float*)(smem + WP_OFF);
  u16*      s_uw = (u16*)(smem + UW_OFF);
  u16*      s_x  = (u16*)(smem + X_OFF);

  // ---- phase 1: schedule + wproj + Uw staging --------------------------------
  if (tid < 62) {
    s_sc[tid] = sched[d * 62 + tid];
    float acc = 0.f;
    for (int p = 0; p < 16; ++p) acc += Pw[(d * 16 + p) * 62 + tid] * psw[d * 16 + p];
    s_wp[tid] = acc;   // wproj[d][pi] = sum_p P_w[d,p,pi] * ps_w[d*16+p]
  }
  for (int n = tid; n < 132; n += 256) {
    u32 v0 = 0, v1 = 0, v2 = 0, v3 = 0;
    if (n < 128) {
      const float* up = Uw + (d * 128 + n) * 5;
      v0 = (u32)f2bf(up[0]) | ((u32)f2bf(up[1]) << 16);
      v1 = (u32)f2bf(up[2]) | ((u32)f2bf(up[3]) << 16);
      v2 = (u32)f2bf(up[4]);
    }
    uint4 val; val.x = v0; val.y = v1; val.z = v2; val.w = v3;
    *(uint4*)(s_uw + n * 8) = val;
  }
  __syncthreads();

  // ---- phase 2: x staging (needs perm from schedule) + W frags ---------------
  for (int idx = tid; idx < 63 * 16; idx += 256) {
    int pi = idx >> 4, b = idx & 15;
    u32 v0 = 0, v1 = 0, v2 = 0, v3 = 0;
    if (pi < 62 && b < 8) {
      int e = (int)(s_sc[pi] & 63u);
      const float* xp = x + (((size_t)(b0 + b) * 16 + t) * 62 + e) * 5;
      v0 = (u32)f2bf(xp[0]) | ((u32)f2bf(xp[1]) << 16);
      v1 = (u32)f2bf(xp[2]) | ((u32)f2bf(xp[3]) << 16);
      v2 = (u32)f2bf(xp[4]);
    }
    uint4 val; val.x = v0; val.y = v1; val.z = v2; val.w = v3;
    *(uint4*)(s_x + idx * 8) = val;
  }

  // W B^T-fragments (row n of W, 8 consecutive k) -> registers, once.
  bf16x8 wf[2][4];
  float bias[2];
#pragma unroll
  for (int nt = 0; nt < 2; ++nt) {
    const int n = wid * 32 + nt * 16 + l15;
#pragma unroll
    for (int kc = 0; kc < 4; ++kc) {
      const float* wr = Ww + ((size_t)(d * 128 + n) * 128) + kc * 32 + lhi * 8;
      float4 a = *(const float4*)wr, b = *(const float4*)(wr + 4);
      bf16x8 f;
      f[0] = (short)f2bf(a.x); f[1] = (short)f2bf(a.y);
      f[2] = (short)f2bf(a.z); f[3] = (short)f2bf(a.w);
      f[4] = (short)f2bf(b.x); f[5] = (short)f2bf(b.y);
      f[6] = (short)f2bf(b.z); f[7] = (short)f2bf(b.w);
      wf[nt][kc] = f;
    }
    bias[nt] = Ub[d * 128 + n] + Wb[d * 128 + n] + spbs[d * 128 + n];
  }
  __syncthreads();

  bf16x8 uwf0 = *(const bf16x8*)(s_uw + (wid * 32 + l15) * 8 + lhi * 8);
  bf16x8 uwf1 = *(const bf16x8*)(s_uw + (wid * 32 + 16 + l15) * 8 + lhi * 8);

  f32x4 macc0 = {0.f, 0.f, 0.f, 0.f}, macc1 = {0.f, 0.f, 0.f, 0.f};

  // ---- 62-step scan ----------------------------------------------------------
  for (int pi = 0; pi < 62; ++pi) {
    const unsigned sv = s_sc[pi];
    const int snew  = (int)((sv >> 6) & 31u);
    const int nbcnt = (int)((sv >> 11) & 3u);

    bf16x8 xa = *(const bf16x8*)(s_x + (pi * 16 + l15) * 8 + lhi * 8);
    if (lane >= 16) { const bf16x8 z = {0,0,0,0,0,0,0,0}; xa = z; } // k>=8 of padded C dim

    f32x4 acc0 = {0.f,0.f,0.f,0.f}, acc1 = {0.f,0.f,0.f,0.f};
    acc0 = __builtin_amdgcn_mfma_f32_16x16x32_bf16(xa, uwf0, acc0, 0, 0, 0);
    acc1 = __builtin_amdgcn_mfma_f32_16x16x32_bf16(xa, uwf1, acc1, 0, 0, 0);

    auto slot_mac = [&](int sl) {
      const char* sb = smem + sl * SLOT_BYTES + (l15 & 7) * 272 + lhi * 16;
#pragma unroll
      for (int kc = 0; kc < 4; ++kc) {
        bf16x8 a = *(const bf16x8*)(sb + kc * 64);
        acc0 = __builtin_amdgcn_mfma_f32_16x16x32_bf16(a, wf[0][kc], acc0, 0, 0, 0);
        acc1 = __builtin_amdgcn_mfma_f32_16x16x32_bf16(a, wf[1][kc], acc1, 0, 0, 0);
      }
    };
    if (nbcnt > 0) slot_mac((int)((sv >> 13) & 31u));
    if (nbcnt > 1) slot_mac((int)((sv >> 18) & 31u));
    if (nbcnt > 2) slot_mac((int)((sv >> 23) & 31u));

    // epilogue: relu, m-projection accumulate, write h (bf16) into new slot
    const float wp = s_wp[pi];
    char* dst = smem + snew * SLOT_BYTES;
#pragma unroll
    for (int r = 0; r < 4; ++r) {
      float h0 = fmaxf(acc0[r] + bias[0], 0.f);
      float h1 = fmaxf(acc1[r] + bias[1], 0.f);
      macc0[r] += h0 * wp;
      macc1[r] += h1 * wp;
      if (lhi < 2) {  // only rows 0..7 are real batch rows (BM=8)
        const int rr = lhi * 4 + r;
        *(u16*)(dst + rr * 272 + (wid * 64 + l15 * 2))      = f2bf(h0);
        *(u16*)(dst + rr * 272 + (wid * 64 + 32 + l15 * 2)) = f2bf(h1);
      }
    }
    __syncthreads();
  }

  // ---- store per-direction partial of m --------------------------------------
  if (lhi < 2) {
#pragma unroll
    for (int r = 0; r < 4; ++r) {
      const int brow = b0 + lhi * 4 + r;
      const int n0 = wid * 32 + l15;
      float* pp = part + (((size_t)d * 16 + t) * 128 + brow) * 128;
      pp[n0]      = macc0[r];
      pp[n0 + 16] = macc1[r];
    }
  }
}

// ---------------------------------------------------------------------------
// Reduce 4 direction-partials + C0 -> ms (bf16).
// ---------------------------------------------------------------------------
__global__ __launch_bounds__(256) void reduce_ms_kernel(
    const float* __restrict__ part, const float* __restrict__ Pb,
    const float* __restrict__ psw,  const float* __restrict__ psb,
    u16* __restrict__ msbf)
{
  const int idx = blockIdx.x * 256 + threadIdx.x;   // 262144 total
  float c0 = psb[0];
  for (int i = 0; i < 64; ++i) c0 += Pb[i] * psw[i];
  float s = c0 + part[idx] + part[262144 + idx] + part[2 * 262144 + idx] + part[3 * 262144 + idx];
  msbf[idx] = f2bf(s);
}

// ---------------------------------------------------------------------------
// TRNN (fwd+bwd) + collapsed projections -> out[128][3]. 8 WGs (16 b each).
// ---------------------------------------------------------------------------
__global__ __launch_bounds__(256) void trnn_kernel(
    const u16* __restrict__ msbf, float* __restrict__ hsws,
    const float* __restrict__ frs, const float* __restrict__ frsb,
    const float* __restrict__ fvs, const float* __restrict__ fvsb,
    const float* __restrict__ fbs, const float* __restrict__ fpj, const float* __restrict__ fpjb,
    const float* __restrict__ brs, const float* __restrict__ brsb,
    const float* __restrict__ bvs, const float* __restrict__ bvsb,
    const float* __restrict__ bbs, const float* __restrict__ bpj, const float* __restrict__ bpjb,
    const float* __restrict__ fp1w, const float* __restrict__ fp1b,
    const float* __restrict__ fp2w, const float* __restrict__ fp2b,
    const float* __restrict__ bp1w, const float* __restrict__ bp1b,
    const float* __restrict__ bp2w, const float* __restrict__ bp2b,
    float* __restrict__ out)
{
  __shared__ u16  h_dbl[2][16][136];
  __shared__ float sred[2][16][16];
  const int tid = threadIdx.x;
  const int lane = tid & 63, wid = tid >> 6;
  const int l15 = lane & 15, lhi = lane >> 4;
  const int b0 = blockIdx.x * 16;

  for (int dir = 0; dir < 2; ++dir) {
    const float* rs  = dir ? brs  : frs;
    const float* rsb = dir ? brsb : frsb;
    const float* vs  = dir ? bvs  : fvs;
    const float* vsb = dir ? bvsb : fvsb;
    const float* bs  = dir ? bbs  : fbs;

    bf16x8 rf[2][4], vf[2][4];
    float bias[2];
#pragma unroll
    for (int nt = 0; nt < 2; ++nt) {
      const int n = wid * 32 + nt * 16 + l15;
#pragma unroll
      for (int kc = 0; kc < 4; ++kc) {
        const float* p = rs + (size_t)n * 128 + kc * 32 + lhi * 8;
        const float* q = vs + (size_t)n * 128 + kc * 32 + lhi * 8;
        bf16x8 a, b;
#pragma unroll
        for (int j = 0; j < 8; ++j) { a[j] = (short)f2bf(p[j]); b[j] = (short)f2bf(q[j]); }
        rf[nt][kc] = a; vf[nt][kc] = b;
      }
      bias[nt] = rsb[n] + vsb[n] + bs[n];
    }
    for (int i = tid; i < 2 * 16 * 136; i += 256) ((u16*)h_dbl)[i] = 0;
    __syncthreads();

    int cur = 0;
    for (int tt2 = 0; tt2 < 16; ++tt2) {
      const int tt = dir ? (15 - tt2) : tt2;
      f32x4 acc0 = {0.f,0.f,0.f,0.f}, acc1 = {0.f,0.f,0.f,0.f};
#pragma unroll
      for (int kc = 0; kc < 4; ++kc) {
        bf16x8 ma = *(const bf16x8*)(msbf + ((size_t)tt * 128 + b0 + l15) * 128 + kc * 32 + lhi * 8);
        bf16x8 ha = *(const bf16x8*)(&h_dbl[cur][l15][kc * 32 + lhi * 8]);
        acc0 = __builtin_amdgcn_mfma_f32_16x16x32_bf16(ma, rf[0][kc], acc0, 0, 0, 0);
        acc0 = __builtin_amdgcn_mfma_f32_16x16x32_bf16(ha, vf[0][kc], acc0, 0, 0, 0);
        acc1 = __builtin_amdgcn_mfma_f32_16x16x32_bf16(ma, rf[1][kc], acc1, 0, 0, 0);
        acc1 = __builtin_amdgcn_mfma_f32_16x16x32_bf16(ha, vf[1][kc], acc1, 0, 0, 0);
      }
#pragma unroll
      for (int r = 0; r < 4; ++r) {
        const int row = lhi * 4 + r;
        float h0 = fmaxf(acc0[r] + bias[0], 0.f);
        float h1 = fmaxf(acc1[r] + bias[1], 0.f);
        h_dbl[cur ^ 1][row][wid * 32 + l15]      = f2bf(h0);
        h_dbl[cur ^ 1][row][wid * 32 + 16 + l15] = f2bf(h1);
        float* hp = hsws + ((size_t)tt2 * 128 + b0 + row) * 128;
        hp[wid * 32 + l15]      = h0;
        hp[wid * 32 + 16 + l15] = h1;
      }
      __syncthreads();
      cur ^= 1;
    }
    __threadfence();
    __syncthreads();
    {
      const int tq = tid >> 4, bq = tid & 15;
      const float* hp = hsws + ((size_t)tq * 128 + b0 + bq) * 128;
      const float* w1 = dir ? bp1w : fp1w;
      float s = 0.f;
      for (int n = 0; n < 128; n += 4) {
        float4 hv = *(const float4*)(hp + n);
        float4 wv = *(const float4*)(w1 + n);
        s += hv.x * wv.x + hv.y * wv.y + hv.z * wv.z + hv.w * wv.w;
      }
      sred[dir][tq][bq] = s;
    }
    __syncthreads();
  }

  if (tid < 48) {
    const int b = tid / 3, c = tid % 3;
    float val = 0.f;
    {
      float S1 = 0.f;
      for (int h = 0; h < 128; ++h) S1 += fp1w[h];
      float C = fp2b[c];
      for (int p = 0; p < 8; ++p) C += (fpjb[p] * S1 + fp1b[0]) * fp2w[c * 8 + p];
      val += C;
      for (int t2 = 0; t2 < 16; ++t2) {
        float g = 0.f;
        for (int p = 0; p < 8; ++p) g += fp2w[c * 8 + p] * fpj[p * 16 + t2];
        val += sred[0][t2][b] * g;
      }
    }
    {
      float S1 = 0.f;
      for (int h = 0; h < 128; ++h) S1 += bp1w[h];
      float C = bp2b[c];
      for (int p = 0; p < 8; ++p) C += (bpjb[p] * S1 + bp1b[0]) * bp2w[c * 8 + p];
      val += C;
      for (int t2 = 0; t2 < 16; ++t2) {
        float g = 0.f;
        for (int p = 0; p < 8; ++p) g += bp2w[c * 8 + p] * bpj[p * 16 + t2];
        val += sred[1][t2][b] * g;
      }
    }
    out[(b0 + b) * 3 + c] = val;
  }
}

// ---------------------------------------------------------------------------
// Host: rebuild the (constant) graph + static slot schedule each call.
// ---------------------------------------------------------------------------
static const int COOR[62][2] = {
  {1,4},{1,5},{1,6},{2,4},{2,6},
  {3,1},{3,2},{3,3},{3,4},{3,5},{3,6},{3,7},{3,8},{3,9},
  {4,1},{4,2},{4,3},{4,4},{4,5},{4,6},{4,7},{4,8},{4,9},
  {5,1},{5,2},{5,3},{5,4},{5,5},{5,6},{5,7},{5,8},{5,9},
  {6,1},{6,2},{6,3},{6,4},{6,5},{6,6},{6,7},{6,8},{6,9},
  {7,1},{7,2},{7,3},{7,4},{7,5},{7,6},{7,7},{7,8},{7,9},
  {8,2},{8,3},{8,4},{8,5},{8,6},{8,7},{8,8},
  {9,3},{9,4},{9,5},{9,6},{9,7}};

static const int DIRS[4][62] = {
  {1,2,3,4,5,6,7,8,9,10,11,12,13,14,15,16,17,18,19,20,21,22,23,24,25,26,27,28,29,30,
   31,32,33,34,35,36,37,38,39,40,41,42,43,44,45,46,47,48,49,50,
   58,52,53,54,55,56,62,60,61,51,57,59},
  {59,57,51,61,60,62,56,55,54,53,52,58,50,41,32,23,14,49,40,31,22,13,48,39,30,21,12,
   47,38,29,20,11,46,37,28,19,10,45,36,27,18,9,44,35,26,17,8,43,34,25,16,7,42,33,24,
   15,6,5,4,3,2,1},
  {59,57,51,61,60,62,56,55,54,53,52,58,50,49,48,47,46,45,44,43,42,41,40,39,38,37,36,
   35,34,33,32,31,30,29,28,27,26,25,24,23,22,21,20,19,18,17,16,15,14,13,12,11,10,9,
   8,7,6,5,4,3,2,1},
  {1,2,3,4,5,6,15,24,33,42,7,16,25,34,43,8,17,26,35,44,9,18,27,36,45,10,19,28,37,46,
   11,20,29,38,47,12,21,30,39,48,13,22,31,40,49,14,23,32,41,50,
   58,52,53,54,55,56,62,60,61,51,57,59}};

static void build_sched(unsigned* outv) {  // outv[4*62], packed
  static const int OFFS[4][3][2] = {
    {{0,-1},{-1,-1},{-1,0}},
    {{0, 1},{-1, 0},{-1,1}},
    {{0,-1},{ 1,-1},{ 1,0}},
    {{0,-1},{-1,-1},{-1,0}}};
  for (int d = 0; d < 4; ++d) {
    int pos_of[63];
    for (int p = 0; p < 62; ++p) pos_of[DIRS[d][p]] = p;
    int nb[62][3], nc[62], last[62];
    for (int p = 0; p < 62; ++p) { nc[p] = 0; last[p] = -1; }
    for (int p = 0; p < 62; ++p) {
      const int e = DIRS[d][p];
      const int ci = COOR[e - 1][0], cj = COOR[e - 1][1];
      for (int o = 0; o < 3; ++o) {
        const int ni = ci + OFFS[d][o][0], nj = cj + OFFS[d][o][1];
        int q = 0;
        for (int k = 0; k < 62; ++k)
          if (COOR[k][0] == ni && COOR[k][1] == nj) { q = k + 1; break; }
        if (q) {
          const int qp = pos_of[q];
          if (qp < p) { nb[p][nc[p]++] = qp; if (p > last[qp]) last[qp] = p; }
        }
      }
    }
    int slot_of[62];
    for (int p = 0; p < 62; ++p) {
      bool used[NSLOT] = {};
      for (int j = 0; j < p; ++j)
        if (last[j] >= p) used[slot_of[j]] = true;   // still live -> occupied
      int s = 0;
      while (s < NSLOT - 1 && used[s]) ++s;
      slot_of[p] = s;
      unsigned v = (unsigned)(DIRS[d][p] - 1)
                 | ((unsigned)s << 6)
                 | ((unsigned)nc[p] << 11)
                 | ((unsigned)(nc[p] > 0 ? slot_of[nb[p][0]] : 0) << 13)
                 | ((unsigned)(nc[p] > 1 ? slot_of[nb[p][1]] : 0) << 18)
                 | ((unsigned)(nc[p] > 2 ? slot_of[nb[p][2]] : 0) << 23);
      outv[d * 62 + p] = v;
    }
  }
}

extern "C" void kernel_launch(void* const* d_in, const int* in_sizes, int n_in,
                              void* d_out, int out_size, void* d_ws, size_t ws_size,
                              hipStream_t stream)
{
  (void)in_sizes; (void)n_in; (void)out_size; (void)ws_size;
  const float* x    = (const float*)d_in[0];
  const float* Uw   = (const float*)d_in[3];
  const float* Ub   = (const float*)d_in[4];
  const float* Ww   = (const float*)d_in[5];
  const float* Wb   = (const float*)d_in[6];
  const float* spbs = (const float*)d_in[7];
  const float* Pw   = (const float*)d_in[8];
  const float* Pb   = (const float*)d_in[9];
  const float* psw  = (const float*)d_in[10];
  const float* psb  = (const float*)d_in[11];
  const float* frs  = (const float*)d_in[12];
  const float* frsb = (const float*)d_in[13];
  const float* fvs  = (const float*)d_in[14];
  const float* fvsb = (const float*)d_in[15];
  const float* fbs  = (const float*)d_in[16];
  const float* fpj  = (const float*)d_in[17];
  const float* fpjb = (const float*)d_in[18];
  const float* brs  = (const float*)d_in[19];
  const float* brsb = (const float*)d_in[20];
  const float* bvs  = (const float*)d_in[21];
  const float* bvsb = (const float*)d_in[22];
  const float* bbs  = (const float*)d_in[23];
  const float* bpj  = (const float*)d_in[24];
  const float* bpjb = (const float*)d_in[25];
  const float* fp1w = (const float*)d_in[26];
  const float* fp1b = (const float*)d_in[27];
  const float* fp2w = (const float*)d_in[28];
  const float* fp2b = (const float*)d_in[29];
  const float* bp1w = (const float*)d_in[30];
  const float* bp1b = (const float*)d_in[31];
  const float* bp2w = (const float*)d_in[32];
  const float* bp2b = (const float*)d_in[33];

  char* ws = (char*)d_ws;
  float*    part = (float*)(ws);                               // 4 MiB: [4][16][128][128] f32
  u16*      msbf = (u16*)(ws + 4194304);                       // 512 KiB: [16][128][128] bf16
  float*    hsws = (float*)(ws + 4194304 + 524288);            // 1 MiB: [16][128][128] f32
  unsigned* schd = (unsigned*)(ws + 4194304 + 524288 + 1048576); // 992 B packed schedule

  static unsigned h_sched[4 * 62];
  build_sched(h_sched);
  hipMemcpyAsync(schd, h_sched, sizeof(h_sched), hipMemcpyHostToDevice, stream);

  srnn_kernel<<<dim3(1024), dim3(256), 0, stream>>>(x, Uw, Ub, Ww, Wb, spbs, Pw, psw, schd, part);
  reduce_ms_kernel<<<dim3(1024), dim3(256), 0, stream>>>(part, Pb, psw, psb, msbf);
  trnn_kernel<<<dim3(8), dim3(256), 0, stream>>>(msbf, hsws,
      frs, frsb, fvs, fvsb, fbs, fpj, fpjb,
      brs, brsb, bvs, bvsb, bbs, bpj, bpjb,
      fp1w, fp1b, fp2w, fp2b, bp1w, bp1b, bp2w, bp2b,
      (float*)d_out);
}

// Round 2
// 112.213 us; speedup vs baseline: 1.3982x; 1.3982x over previous
//
#include <hip/hip_runtime.h>

typedef unsigned short u16;
typedef unsigned int   u32;

using bf16x8 = __attribute__((ext_vector_type(8))) short;
using f32x4  = __attribute__((ext_vector_type(4))) float;

__device__ __forceinline__ u16 f2bf(float f) {
  u32 u = __float_as_uint(f);
  u32 r = u + 0x7FFFu + ((u >> 16) & 1u);   // round-to-nearest-even
  return (u16)(r >> 16);
}

// ---------------------------------------------------------------------------
// SRNN v2: one WG per (t-pair, d, b-block of 8). MFMA M rows 0-7 = t0 batch,
// rows 8-15 = t1 batch (same d => same schedule/weights). 512 WGs, one
// occupancy round at 2 WG/CU. h history slots in dynamic LDS, XOR-swizzled,
// k-interleaved so each lane writes one b32 (n, n+16) pair.
// ---------------------------------------------------------------------------
#define NSLOT 15
#define SLOT_BYTES 4096                       // [16 rows][128 cols] bf16, swizzled
#define POOL_BYTES (NSLOT * SLOT_BYTES)       // 61440
#define X_OFF      POOL_BYTES                 // 61440
#define X_BYTES    (62 * 16 * 16)             // 15872  [pi][16 rows][8 ch] bf16
#define UW_OFF     (X_OFF + X_BYTES)          // 77312
#define UW_BYTES   (128 * 8 * 2)              // 2048   [n][8 ch] bf16
#define WP_OFF     (UW_OFF + UW_BYTES)        // 79360  wproj[62] f32
#define SC_OFF     (WP_OFF + 256)             // 79616  packed sched[62] u32
#define SMEM_TOTAL (SC_OFF + 256)             // 79872 dynamic LDS

__global__ __launch_bounds__(256) void srnn_kernel(
    const float* __restrict__ x,    const float* __restrict__ Uw,
    const float* __restrict__ Ub,   const float* __restrict__ Ww,
    const float* __restrict__ Wb,   const float* __restrict__ spbs,
    const float* __restrict__ Pw,   const float* __restrict__ psw,
    const unsigned* __restrict__ sched, float* __restrict__ part)
{
  extern __shared__ __align__(16) char smem[];
  const int tid  = threadIdx.x;
  const int lane = tid & 63, wid = tid >> 6;
  const int l15  = lane & 15, lhi = lane >> 4;
  const int bx = blockIdx.x;
  const int bb = bx & 15, d = (bx >> 4) & 3, tp = bx >> 6;
  const int b0 = bb * 8, t0 = tp * 2;

  unsigned* s_sc = (unsigned*)(smem + SC_OFF);
  float*    s_wp = (float*)(smem + WP_OFF);
  u16*      s_uw = (u16*)(smem + UW_OFF);
  u16*      s_x  = (u16*)(smem + X_OFF);

  // ---- phase 1: schedule + wproj + Uw staging --------------------------------
  if (tid < 62) {
    s_sc[tid] = sched[d * 62 + tid];
    float acc = 0.f;
    for (int p = 0; p < 16; ++p) acc += Pw[(d * 16 + p) * 62 + tid] * psw[d * 16 + p];
    s_wp[tid] = acc;
  }
  for (int n = tid; n < 128; n += 256) {
    const float* up = Uw + (d * 128 + n) * 5;
    uint4 val;
    val.x = (u32)f2bf(up[0]) | ((u32)f2bf(up[1]) << 16);
    val.y = (u32)f2bf(up[2]) | ((u32)f2bf(up[3]) << 16);
    val.z = (u32)f2bf(up[4]);
    val.w = 0;
    *(uint4*)(s_uw + n * 8) = val;
  }
  __syncthreads();

  // ---- phase 2: x staging (rows 0-7 = t0, 8-15 = t1) + W frags ---------------
  for (int idx = tid; idx < 62 * 16; idx += 256) {
    const int pi = idx >> 4, row = idx & 15;
    const int b = row & 7, tsel = row >> 3;
    const int e = (int)(s_sc[pi] & 63u);
    const float* xp = x + (((size_t)(b0 + b) * 16 + (t0 + tsel)) * 62 + e) * 5;
    uint4 val;
    val.x = (u32)f2bf(xp[0]) | ((u32)f2bf(xp[1]) << 16);
    val.y = (u32)f2bf(xp[2]) | ((u32)f2bf(xp[3]) << 16);
    val.z = (u32)f2bf(xp[4]);
    val.w = 0;
    *(uint4*)(s_x + idx * 8) = val;
  }

  // W B-fragments with the k-interleave permutation (physical q in each
  // 32-block: q=2i+j <-> logical k = i + 16j). Matches the b32 h-writes.
  bf16x8 wf[2][4];
  float bias[2];
#pragma unroll
  for (int nt = 0; nt < 2; ++nt) {
    const int n = wid * 32 + nt * 16 + l15;
    const float* wr = Ww + (size_t)(d * 128 + n) * 128;
#pragma unroll
    for (int kc = 0; kc < 4; ++kc) {
      bf16x8 f;
#pragma unroll
      for (int j = 0; j < 8; ++j) {
        const int kq = lhi * 8 + j;
        const int klog = kc * 32 + (kq >> 1) + ((kq & 1) << 4);
        f[j] = (short)f2bf(wr[klog]);
      }
      wf[nt][kc] = f;
    }
    bias[nt] = Ub[d * 128 + n] + Wb[d * 128 + n] + spbs[d * 128 + n];
  }
  __syncthreads();

  bf16x8 uwf0 = *(const bf16x8*)(s_uw + (wid * 32 + l15) * 8 + lhi * 8);
  bf16x8 uwf1 = *(const bf16x8*)(s_uw + (wid * 32 + 16 + l15) * 8 + lhi * 8);

  f32x4 macc0 = {0.f, 0.f, 0.f, 0.f}, macc1 = {0.f, 0.f, 0.f, 0.f};

  const int swz_r = ((l15 & 7) << 4);                 // read-side XOR (row = l15)
  const int wcol  = wid * 64 + l15 * 4;               // write col bytes (pre-XOR)

  // ---- 62-step scan ----------------------------------------------------------
  for (int pi = 0; pi < 62; ++pi) {
    const unsigned sv = s_sc[pi];
    const int snew  = (int)((sv >> 6) & 31u);
    const int nbcnt = (int)((sv >> 11) & 3u);

    bf16x8 xa = *(const bf16x8*)(s_x + (pi * 16 + l15) * 8);
    if (lhi != 0) { const bf16x8 z = {0,0,0,0,0,0,0,0}; xa = z; }  // k>=8 zero

    f32x4 acc0 = {0.f,0.f,0.f,0.f}, acc1 = {0.f,0.f,0.f,0.f};
    acc0 = __builtin_amdgcn_mfma_f32_16x16x32_bf16(xa, uwf0, acc0, 0, 0, 0);
    acc1 = __builtin_amdgcn_mfma_f32_16x16x32_bf16(xa, uwf1, acc1, 0, 0, 0);

    auto slot_mac = [&](int sl) {
      const char* sb = smem + sl * SLOT_BYTES + l15 * 256;
#pragma unroll
      for (int kc = 0; kc < 4; ++kc) {
        bf16x8 a = *(const bf16x8*)(sb + ((kc * 64 + lhi * 16) ^ swz_r));
        acc0 = __builtin_amdgcn_mfma_f32_16x16x32_bf16(a, wf[0][kc], acc0, 0, 0, 0);
        acc1 = __builtin_amdgcn_mfma_f32_16x16x32_bf16(a, wf[1][kc], acc1, 0, 0, 0);
      }
    };
    if (nbcnt > 0) slot_mac((int)((sv >> 13) & 31u));
    if (nbcnt > 1) slot_mac((int)((sv >> 18) & 31u));
    if (nbcnt > 2) slot_mac((int)((sv >> 23) & 31u));

    // epilogue: relu, m-projection accumulate, packed b32 h-write (n, n+16)
    const float wp = s_wp[pi];
    char* dst = smem + snew * SLOT_BYTES;
#pragma unroll
    for (int r = 0; r < 4; ++r) {
      const int row = lhi * 4 + r;
      float h0 = fmaxf(acc0[r] + bias[0], 0.f);
      float h1 = fmaxf(acc1[r] + bias[1], 0.f);
      macc0[r] += h0 * wp;
      macc1[r] += h1 * wp;
      const u32 wv = (u32)f2bf(h0) | ((u32)f2bf(h1) << 16);
      *(u32*)(dst + row * 256 + (wcol ^ ((row & 7) << 4))) = wv;
    }
    __syncthreads();
  }

  // ---- store per-(d,t) partial of m ------------------------------------------
#pragma unroll
  for (int r = 0; r < 4; ++r) {
    const int row = lhi * 4 + r;
    const int t = t0 + (row >> 3);
    const int brow = b0 + (row & 7);
    const int n0 = wid * 32 + l15;
    float* pp = part + (((size_t)d * 16 + t) * 128 + brow) * 128;
    pp[n0]      = macc0[r];
    pp[n0 + 16] = macc1[r];
  }
}

// ---------------------------------------------------------------------------
// Reduce 4 direction-partials + C0 -> ms (bf16).
// ---------------------------------------------------------------------------
__global__ __launch_bounds__(256) void reduce_ms_kernel(
    const float* __restrict__ part, const float* __restrict__ Pb,
    const float* __restrict__ psw,  const float* __restrict__ psb,
    u16* __restrict__ msbf)
{
  const int idx = blockIdx.x * 256 + threadIdx.x;   // 262144 total
  float c0 = psb[0];
  for (int i = 0; i < 64; ++i) c0 += Pb[i] * psw[i];
  float s = c0 + part[idx] + part[262144 + idx] + part[2 * 262144 + idx] + part[3 * 262144 + idx];
  msbf[idx] = f2bf(s);
}

// ---------------------------------------------------------------------------
// TRNN fwd+bwd fused into one 16-step loop + collapsed projections.
// 8 WGs (16 batch each).
// ---------------------------------------------------------------------------
__global__ __launch_bounds__(256) void trnn_kernel(
    const u16* __restrict__ msbf, float* __restrict__ hsws,
    const float* __restrict__ frs, const float* __restrict__ frsb,
    const float* __restrict__ fvs, const float* __restrict__ fvsb,
    const float* __restrict__ fbs, const float* __restrict__ fpj, const float* __restrict__ fpjb,
    const float* __restrict__ brs, const float* __restrict__ brsb,
    const float* __restrict__ bvs, const float* __restrict__ bvsb,
    const float* __restrict__ bbs, const float* __restrict__ bpj, const float* __restrict__ bpjb,
    const float* __restrict__ fp1w, const float* __restrict__ fp1b,
    const float* __restrict__ fp2w, const float* __restrict__ fp2b,
    const float* __restrict__ bp1w, const float* __restrict__ bp1b,
    const float* __restrict__ bp2w, const float* __restrict__ bp2b,
    float* __restrict__ out)
{
  __shared__ u16  hbuf[2][2][16][136];   // [dir][buf][row][col]
  __shared__ float sred[2][16][16];
  const int tid = threadIdx.x;
  const int lane = tid & 63, wid = tid >> 6;
  const int l15 = lane & 15, lhi = lane >> 4;
  const int b0 = blockIdx.x * 16;

  // prologue: weight fragments for BOTH dirs
  bf16x8 rf[2][2][4], vf[2][2][4];
  float bias[2][2];
#pragma unroll
  for (int dir = 0; dir < 2; ++dir) {
    const float* rs  = dir ? brs  : frs;
    const float* rsb = dir ? brsb : frsb;
    const float* vs  = dir ? bvs  : fvs;
    const float* vsb = dir ? bvsb : fvsb;
    const float* bs  = dir ? bbs  : fbs;
#pragma unroll
    for (int nt = 0; nt < 2; ++nt) {
      const int n = wid * 32 + nt * 16 + l15;
#pragma unroll
      for (int kc = 0; kc < 4; ++kc) {
        const float* p = rs + (size_t)n * 128 + kc * 32 + lhi * 8;
        const float* q = vs + (size_t)n * 128 + kc * 32 + lhi * 8;
        bf16x8 a, b;
#pragma unroll
        for (int j = 0; j < 8; ++j) { a[j] = (short)f2bf(p[j]); b[j] = (short)f2bf(q[j]); }
        rf[dir][nt][kc] = a; vf[dir][nt][kc] = b;
      }
      bias[dir][nt] = rsb[n] + vsb[n] + bs[n];
    }
  }
  for (int i = tid; i < 2 * 2 * 16 * 136; i += 256) (&hbuf[0][0][0][0])[i] = 0;
  __syncthreads();

  int cur = 0;
  for (int tt2 = 0; tt2 < 16; ++tt2) {
#pragma unroll
    for (int dir = 0; dir < 2; ++dir) {
      const int tt = dir ? (15 - tt2) : tt2;
      f32x4 acc0 = {0.f,0.f,0.f,0.f}, acc1 = {0.f,0.f,0.f,0.f};
#pragma unroll
      for (int kc = 0; kc < 4; ++kc) {
        bf16x8 ma = *(const bf16x8*)(msbf + ((size_t)tt * 128 + b0 + l15) * 128 + kc * 32 + lhi * 8);
        bf16x8 ha = *(const bf16x8*)(&hbuf[dir][cur][l15][kc * 32 + lhi * 8]);
        acc0 = __builtin_amdgcn_mfma_f32_16x16x32_bf16(ma, rf[dir][0][kc], acc0, 0, 0, 0);
        acc0 = __builtin_amdgcn_mfma_f32_16x16x32_bf16(ha, vf[dir][0][kc], acc0, 0, 0, 0);
        acc1 = __builtin_amdgcn_mfma_f32_16x16x32_bf16(ma, rf[dir][1][kc], acc1, 0, 0, 0);
        acc1 = __builtin_amdgcn_mfma_f32_16x16x32_bf16(ha, vf[dir][1][kc], acc1, 0, 0, 0);
      }
#pragma unroll
      for (int r = 0; r < 4; ++r) {
        const int row = lhi * 4 + r;
        float h0 = fmaxf(acc0[r] + bias[dir][0], 0.f);
        float h1 = fmaxf(acc1[r] + bias[dir][1], 0.f);
        hbuf[dir][cur ^ 1][row][wid * 32 + l15]      = f2bf(h0);
        hbuf[dir][cur ^ 1][row][wid * 32 + 16 + l15] = f2bf(h1);
        float* hp = hsws + (((size_t)dir * 16 + tt2) * 128 + b0 + row) * 128;
        hp[wid * 32 + l15]      = h0;
        hp[wid * 32 + 16 + l15] = h1;
      }
    }
    __syncthreads();
    cur ^= 1;
  }
  __threadfence();
  __syncthreads();

  {
    const int tq = tid >> 4, bq = tid & 15;
#pragma unroll
    for (int dir = 0; dir < 2; ++dir) {
      const float* hp = hsws + (((size_t)dir * 16 + tq) * 128 + b0 + bq) * 128;
      const float* w1 = dir ? bp1w : fp1w;
      float s = 0.f;
      for (int n = 0; n < 128; n += 4) {
        float4 hv = *(const float4*)(hp + n);
        float4 wv = *(const float4*)(w1 + n);
        s += hv.x * wv.x + hv.y * wv.y + hv.z * wv.z + hv.w * wv.w;
      }
      sred[dir][tq][bq] = s;
    }
  }
  __syncthreads();

  if (tid < 48) {
    const int b = tid / 3, c = tid % 3;
    float val = 0.f;
    {
      float S1 = 0.f;
      for (int h = 0; h < 128; ++h) S1 += fp1w[h];
      float C = fp2b[c];
      for (int p = 0; p < 8; ++p) C += (fpjb[p] * S1 + fp1b[0]) * fp2w[c * 8 + p];
      val += C;
      for (int t2 = 0; t2 < 16; ++t2) {
        float g = 0.f;
        for (int p = 0; p < 8; ++p) g += fp2w[c * 8 + p] * fpj[p * 16 + t2];
        val += sred[0][t2][b] * g;
      }
    }
    {
      float S1 = 0.f;
      for (int h = 0; h < 128; ++h) S1 += bp1w[h];
      float C = bp2b[c];
      for (int p = 0; p < 8; ++p) C += (bpjb[p] * S1 + bp1b[0]) * bp2w[c * 8 + p];
      val += C;
      for (int t2 = 0; t2 < 16; ++t2) {
        float g = 0.f;
        for (int p = 0; p < 8; ++p) g += bp2w[c * 8 + p] * bpj[p * 16 + t2];
        val += sred[1][t2][b] * g;
      }
    }
    out[(b0 + b) * 3 + c] = val;
  }
}

// ---------------------------------------------------------------------------
// Host: rebuild the (constant) graph + static slot schedule each call.
// ---------------------------------------------------------------------------
static const int COOR[62][2] = {
  {1,4},{1,5},{1,6},{2,4},{2,6},
  {3,1},{3,2},{3,3},{3,4},{3,5},{3,6},{3,7},{3,8},{3,9},
  {4,1},{4,2},{4,3},{4,4},{4,5},{4,6},{4,7},{4,8},{4,9},
  {5,1},{5,2},{5,3},{5,4},{5,5},{5,6},{5,7},{5,8},{5,9},
  {6,1},{6,2},{6,3},{6,4},{6,5},{6,6},{6,7},{6,8},{6,9},
  {7,1},{7,2},{7,3},{7,4},{7,5},{7,6},{7,7},{7,8},{7,9},
  {8,2},{8,3},{8,4},{8,5},{8,6},{8,7},{8,8},
  {9,3},{9,4},{9,5},{9,6},{9,7}};

static const int DIRS[4][62] = {
  {1,2,3,4,5,6,7,8,9,10,11,12,13,14,15,16,17,18,19,20,21,22,23,24,25,26,27,28,29,30,
   31,32,33,34,35,36,37,38,39,40,41,42,43,44,45,46,47,48,49,50,
   58,52,53,54,55,56,62,60,61,51,57,59},
  {59,57,51,61,60,62,56,55,54,53,52,58,50,41,32,23,14,49,40,31,22,13,48,39,30,21,12,
   47,38,29,20,11,46,37,28,19,10,45,36,27,18,9,44,35,26,17,8,43,34,25,16,7,42,33,24,
   15,6,5,4,3,2,1},
  {59,57,51,61,60,62,56,55,54,53,52,58,50,49,48,47,46,45,44,43,42,41,40,39,38,37,36,
   35,34,33,32,31,30,29,28,27,26,25,24,23,22,21,20,19,18,17,16,15,14,13,12,11,10,9,
   8,7,6,5,4,3,2,1},
  {1,2,3,4,5,6,15,24,33,42,7,16,25,34,43,8,17,26,35,44,9,18,27,36,45,10,19,28,37,46,
   11,20,29,38,47,12,21,30,39,48,13,22,31,40,49,14,23,32,41,50,
   58,52,53,54,55,56,62,60,61,51,57,59}};

static void build_sched(unsigned* outv) {  // outv[4*62], packed
  static const int OFFS[4][3][2] = {
    {{0,-1},{-1,-1},{-1,0}},
    {{0, 1},{-1, 0},{-1,1}},
    {{0,-1},{ 1,-1},{ 1,0}},
    {{0,-1},{-1,-1},{-1,0}}};
  for (int d = 0; d < 4; ++d) {
    int pos_of[63];
    for (int p = 0; p < 62; ++p) pos_of[DIRS[d][p]] = p;
    int nb[62][3], nc[62], last[62];
    for (int p = 0; p < 62; ++p) { nc[p] = 0; last[p] = -1; }
    for (int p = 0; p < 62; ++p) {
      const int e = DIRS[d][p];
      const int ci = COOR[e - 1][0], cj = COOR[e - 1][1];
      for (int o = 0; o < 3; ++o) {
        const int ni = ci + OFFS[d][o][0], nj = cj + OFFS[d][o][1];
        int q = 0;
        for (int k = 0; k < 62; ++k)
          if (COOR[k][0] == ni && COOR[k][1] == nj) { q = k + 1; break; }
        if (q) {
          const int qp = pos_of[q];
          if (qp < p) { nb[p][nc[p]++] = qp; if (p > last[qp]) last[qp] = p; }
        }
      }
    }
    int slot_of[62];
    for (int p = 0; p < 62; ++p) {
      bool used[NSLOT] = {};
      for (int j = 0; j < p; ++j)
        if (last[j] >= p) used[slot_of[j]] = true;
      int s = 0;
      while (s < NSLOT - 1 && used[s]) ++s;
      slot_of[p] = s;
      unsigned v = (unsigned)(DIRS[d][p] - 1)
                 | ((unsigned)s << 6)
                 | ((unsigned)nc[p] << 11)
                 | ((unsigned)(nc[p] > 0 ? slot_of[nb[p][0]] : 0) << 13)
                 | ((unsigned)(nc[p] > 1 ? slot_of[nb[p][1]] : 0) << 18)
                 | ((unsigned)(nc[p] > 2 ? slot_of[nb[p][2]] : 0) << 23);
      outv[d * 62 + p] = v;
    }
  }
}

extern "C" void kernel_launch(void* const* d_in, const int* in_sizes, int n_in,
                              void* d_out, int out_size, void* d_ws, size_t ws_size,
                              hipStream_t stream)
{
  (void)in_sizes; (void)n_in; (void)out_size; (void)ws_size;
  const float* x    = (const float*)d_in[0];
  const float* Uw   = (const float*)d_in[3];
  const float* Ub   = (const float*)d_in[4];
  const float* Ww   = (const float*)d_in[5];
  const float* Wb   = (const float*)d_in[6];
  const float* spbs = (const float*)d_in[7];
  const float* Pw   = (const float*)d_in[8];
  const float* Pb   = (const float*)d_in[9];
  const float* psw  = (const float*)d_in[10];
  const float* psb  = (const float*)d_in[11];
  const float* frs  = (const float*)d_in[12];
  const float* frsb = (const float*)d_in[13];
  const float* fvs  = (const float*)d_in[14];
  const float* fvsb = (const float*)d_in[15];
  const float* fbs  = (const float*)d_in[16];
  const float* fpj  = (const float*)d_in[17];
  const float* fpjb = (const float*)d_in[18];
  const float* brs  = (const float*)d_in[19];
  const float* brsb = (const float*)d_in[20];
  const float* bvs  = (const float*)d_in[21];
  const float* bvsb = (const float*)d_in[22];
  const float* bbs  = (const float*)d_in[23];
  const float* bpj  = (const float*)d_in[24];
  const float* bpjb = (const float*)d_in[25];
  const float* fp1w = (const float*)d_in[26];
  const float* fp1b = (const float*)d_in[27];
  const float* fp2w = (const float*)d_in[28];
  const float* fp2b = (const float*)d_in[29];
  const float* bp1w = (const float*)d_in[30];
  const float* bp1b = (const float*)d_in[31];
  const float* bp2w = (const float*)d_in[32];
  const float* bp2b = (const float*)d_in[33];

  char* ws = (char*)d_ws;
  float*    part = (float*)(ws);                        // 4 MiB [4][16][128][128] f32
  u16*      msbf = (u16*)(ws + 4194304);                // 512 KiB [16][128][128] bf16
  float*    hsws = (float*)(ws + 4194304 + 524288);     // 2 MiB [2][16][128][128] f32
  unsigned* schd = (unsigned*)(ws + 4194304 + 524288 + 2097152);

  static unsigned h_sched[4 * 62];
  build_sched(h_sched);
  hipMemcpyAsync(schd, h_sched, sizeof(h_sched), hipMemcpyHostToDevice, stream);

  // dynamic-LDS opt-in (host-side attribute set; not a stream op, capture-safe)
  static bool attr_done = false;
  hipFuncSetAttribute((const void*)srnn_kernel,
                      hipFuncAttributeMaxDynamicSharedMemorySize, SMEM_TOTAL);
  (void)attr_done;

  srnn_kernel<<<dim3(512), dim3(256), SMEM_TOTAL, stream>>>(
      x, Uw, Ub, Ww, Wb, spbs, Pw, psw, schd, part);
  reduce_ms_kernel<<<dim3(1024), dim3(256), 0, stream>>>(part, Pb, psw, psb, msbf);
  trnn_kernel<<<dim3(8), dim3(256), 0, stream>>>(msbf, hsws,
      frs, frsb, fvs, fvsb, fbs, fpj, fpjb,
      brs, brsb, bvs, bvsb, bbs, bpj, bpjb,
      fp1w, fp1b, fp2w, fp2b, bp1w, bp1b, bp2w, bp2b,
      (float*)d_out);
}

// Round 3
// 104.411 us; speedup vs baseline: 1.5026x; 1.0747x over previous
//
#include <hip/hip_runtime.h>

typedef unsigned short u16;
typedef unsigned int   u32;

using bf16x8 = __attribute__((ext_vector_type(8))) short;
using f32x4  = __attribute__((ext_vector_type(4))) float;

__device__ __forceinline__ u16 f2bf(float f) {
  u32 u = __float_as_uint(f);
  u32 r = u + 0x7FFFu + ((u >> 16) & 1u);   // round-to-nearest-even
  return (u16)(r >> 16);
}

// ---------------------------------------------------------------------------
// Compile-time schedule (graph is a hardcoded constant in the reference).
// ---------------------------------------------------------------------------
#define NSLOT 15

struct SchedPack { unsigned v[4 * 62]; };

constexpr int cCOOR[62][2] = {
  {1,4},{1,5},{1,6},{2,4},{2,6},
  {3,1},{3,2},{3,3},{3,4},{3,5},{3,6},{3,7},{3,8},{3,9},
  {4,1},{4,2},{4,3},{4,4},{4,5},{4,6},{4,7},{4,8},{4,9},
  {5,1},{5,2},{5,3},{5,4},{5,5},{5,6},{5,7},{5,8},{5,9},
  {6,1},{6,2},{6,3},{6,4},{6,5},{6,6},{6,7},{6,8},{6,9},
  {7,1},{7,2},{7,3},{7,4},{7,5},{7,6},{7,7},{7,8},{7,9},
  {8,2},{8,3},{8,4},{8,5},{8,6},{8,7},{8,8},
  {9,3},{9,4},{9,5},{9,6},{9,7}};

constexpr int cDIRS[4][62] = {
  {1,2,3,4,5,6,7,8,9,10,11,12,13,14,15,16,17,18,19,20,21,22,23,24,25,26,27,28,29,30,
   31,32,33,34,35,36,37,38,39,40,41,42,43,44,45,46,47,48,49,50,
   58,52,53,54,55,56,62,60,61,51,57,59},
  {59,57,51,61,60,62,56,55,54,53,52,58,50,41,32,23,14,49,40,31,22,13,48,39,30,21,12,
   47,38,29,20,11,46,37,28,19,10,45,36,27,18,9,44,35,26,17,8,43,34,25,16,7,42,33,24,
   15,6,5,4,3,2,1},
  {59,57,51,61,60,62,56,55,54,53,52,58,50,49,48,47,46,45,44,43,42,41,40,39,38,37,36,
   35,34,33,32,31,30,29,28,27,26,25,24,23,22,21,20,19,18,17,16,15,14,13,12,11,10,9,
   8,7,6,5,4,3,2,1},
  {1,2,3,4,5,6,15,24,33,42,7,16,25,34,43,8,17,26,35,44,9,18,27,36,45,10,19,28,37,46,
   11,20,29,38,47,12,21,30,39,48,13,22,31,40,49,14,23,32,41,50,
   58,52,53,54,55,56,62,60,61,51,57,59}};

constexpr int cOFFS[4][3][2] = {
  {{0,-1},{-1,-1},{-1,0}},
  {{0, 1},{-1, 0},{-1,1}},
  {{0,-1},{ 1,-1},{ 1,0}},
  {{0,-1},{-1,-1},{-1,0}}};

constexpr SchedPack make_sched() {
  SchedPack out{};
  for (int d = 0; d < 4; ++d) {
    int pos_of[63] = {};
    for (int p = 0; p < 62; ++p) pos_of[cDIRS[d][p]] = p;
    int nb[62][3] = {};
    int nc[62] = {};
    int last[62] = {};
    for (int p = 0; p < 62; ++p) last[p] = -1;
    for (int p = 0; p < 62; ++p) {
      const int e = cDIRS[d][p];
      const int ci = cCOOR[e - 1][0], cj = cCOOR[e - 1][1];
      for (int o = 0; o < 3; ++o) {
        const int ni = ci + cOFFS[d][o][0], nj = cj + cOFFS[d][o][1];
        int q = 0;
        for (int k = 0; k < 62; ++k)
          if (cCOOR[k][0] == ni && cCOOR[k][1] == nj) { q = k + 1; break; }
        if (q) {
          const int qp = pos_of[q];
          if (qp < p) { nb[p][nc[p]] = qp; nc[p] = nc[p] + 1; if (p > last[qp]) last[qp] = p; }
        }
      }
    }
    int slot_of[62] = {};
    for (int p = 0; p < 62; ++p) {
      bool used[NSLOT] = {};
      for (int j = 0; j < p; ++j)
        if (last[j] >= p) used[slot_of[j]] = true;
      int s = 0;
      while (s < NSLOT - 1 && used[s]) ++s;
      slot_of[p] = s;
      out.v[d * 62 + p] =
          (unsigned)(cDIRS[d][p] - 1)
        | ((unsigned)s << 6)
        | ((unsigned)nc[p] << 11)
        | ((unsigned)(nc[p] > 0 ? slot_of[nb[p][0]] : 0) << 13)
        | ((unsigned)(nc[p] > 1 ? slot_of[nb[p][1]] : 0) << 18)
        | ((unsigned)(nc[p] > 2 ? slot_of[nb[p][2]] : 0) << 23);
    }
  }
  return out;
}

__constant__ SchedPack c_sched = make_sched();

// ---------------------------------------------------------------------------
// SRNN: one WG per (t-pair, d, b-block of 8). Rows 0-7 = t0 batch, 8-15 = t1.
// Per-slot independent accumulators (MFMA chain 13 -> 5); macc deferred past
// the barrier. Slots in dynamic LDS, XOR-swizzled, k-interleaved b32 writes.
// ---------------------------------------------------------------------------
#define SLOT_BYTES 4096                       // [16 rows][128 cols] bf16, swizzled
#define POOL_BYTES (NSLOT * SLOT_BYTES)       // 61440
#define X_OFF      POOL_BYTES                 // 61440
#define X_BYTES    (62 * 16 * 16)             // 15872
#define UW_OFF     (X_OFF + X_BYTES)          // 77312
#define UW_BYTES   (128 * 8 * 2)              // 2048
#define WP_OFF     (UW_OFF + UW_BYTES)        // 79360  wproj[62] f32
#define SC_OFF     (WP_OFF + 256)             // 79616  sched[62] u32
#define SMEM_TOTAL (SC_OFF + 256)             // 79872 dynamic LDS

__global__ __launch_bounds__(256) void srnn_kernel(
    const float* __restrict__ x,    const float* __restrict__ Uw,
    const float* __restrict__ Ub,   const float* __restrict__ Ww,
    const float* __restrict__ Wb,   const float* __restrict__ spbs,
    const float* __restrict__ Pw,   const float* __restrict__ psw,
    float* __restrict__ part)
{
  extern __shared__ __align__(16) char smem[];
  const int tid  = threadIdx.x;
  const int lane = tid & 63, wid = tid >> 6;
  const int l15  = lane & 15, lhi = lane >> 4;
  const int bx = blockIdx.x;
  const int bb = bx & 15, d = (bx >> 4) & 3, tp = bx >> 6;
  const int b0 = bb * 8, t0 = tp * 2;

  unsigned* s_sc = (unsigned*)(smem + SC_OFF);
  float*    s_wp = (float*)(smem + WP_OFF);
  u16*      s_uw = (u16*)(smem + UW_OFF);
  u16*      s_x  = (u16*)(smem + X_OFF);

  // ---- phase 1: schedule + wproj + Uw staging --------------------------------
  if (tid < 62) {
    s_sc[tid] = c_sched.v[d * 62 + tid];
    float acc = 0.f;
    for (int p = 0; p < 16; ++p) acc += Pw[(d * 16 + p) * 62 + tid] * psw[d * 16 + p];
    s_wp[tid] = acc;
  }
  for (int n = tid; n < 128; n += 256) {
    const float* up = Uw + (d * 128 + n) * 5;
    uint4 val;
    val.x = (u32)f2bf(up[0]) | ((u32)f2bf(up[1]) << 16);
    val.y = (u32)f2bf(up[2]) | ((u32)f2bf(up[3]) << 16);
    val.z = (u32)f2bf(up[4]);
    val.w = 0;
    *(uint4*)(s_uw + n * 8) = val;
  }
  __syncthreads();

  // ---- phase 2: x staging + W frags ------------------------------------------
  for (int idx = tid; idx < 62 * 16; idx += 256) {
    const int pi = idx >> 4, row = idx & 15;
    const int b = row & 7, tsel = row >> 3;
    const int e = (int)(s_sc[pi] & 63u);
    const float* xp = x + (((size_t)(b0 + b) * 16 + (t0 + tsel)) * 62 + e) * 5;
    uint4 val;
    val.x = (u32)f2bf(xp[0]) | ((u32)f2bf(xp[1]) << 16);
    val.y = (u32)f2bf(xp[2]) | ((u32)f2bf(xp[3]) << 16);
    val.z = (u32)f2bf(xp[4]);
    val.w = 0;
    *(uint4*)(s_x + idx * 8) = val;
  }

  // W B-fragments with k-interleave (physical q=2i+j <-> logical k=i+16j)
  bf16x8 wf[2][4];
  float bias[2];
#pragma unroll
  for (int nt = 0; nt < 2; ++nt) {
    const int n = wid * 32 + nt * 16 + l15;
    const float* wr = Ww + (size_t)(d * 128 + n) * 128;
#pragma unroll
    for (int kc = 0; kc < 4; ++kc) {
      bf16x8 f;
#pragma unroll
      for (int j = 0; j < 8; ++j) {
        const int kq = lhi * 8 + j;
        const int klog = kc * 32 + (kq >> 1) + ((kq & 1) << 4);
        f[j] = (short)f2bf(wr[klog]);
      }
      wf[nt][kc] = f;
    }
    bias[nt] = Ub[d * 128 + n] + Wb[d * 128 + n] + spbs[d * 128 + n];
  }
  __syncthreads();

  bf16x8 uwf0 = *(const bf16x8*)(s_uw + (wid * 32 + l15) * 8 + lhi * 8);
  bf16x8 uwf1 = *(const bf16x8*)(s_uw + (wid * 32 + 16 + l15) * 8 + lhi * 8);

  f32x4 macc0 = {0.f, 0.f, 0.f, 0.f}, macc1 = {0.f, 0.f, 0.f, 0.f};

  const int swz_r = ((l15 & 7) << 4);
  const int wcol  = wid * 64 + l15 * 4;

  // ---- 62-step scan ----------------------------------------------------------
  for (int pi = 0; pi < 62; ++pi) {
    const unsigned sv = s_sc[pi];
    const int snew  = (int)((sv >> 6) & 31u);
    const int nbcnt = (int)((sv >> 11) & 3u);

    bf16x8 xa = *(const bf16x8*)(s_x + (pi * 16 + l15) * 8);
    if (lhi != 0) { const bf16x8 z = {0,0,0,0,0,0,0,0}; xa = z; }

    // primary acc: x term + slot0 (chain 5); slot1/slot2 independent (chain 4)
    f32x4 aP0 = {0.f,0.f,0.f,0.f}, aP1 = {0.f,0.f,0.f,0.f};
    f32x4 aS0 = {0.f,0.f,0.f,0.f}, aS1 = {0.f,0.f,0.f,0.f};
    f32x4 aT0 = {0.f,0.f,0.f,0.f}, aT1 = {0.f,0.f,0.f,0.f};
    aP0 = __builtin_amdgcn_mfma_f32_16x16x32_bf16(xa, uwf0, aP0, 0, 0, 0);
    aP1 = __builtin_amdgcn_mfma_f32_16x16x32_bf16(xa, uwf1, aP1, 0, 0, 0);

    auto slot_mac = [&](int sl, f32x4& A0, f32x4& A1) {
      const char* sb = smem + sl * SLOT_BYTES + l15 * 256;
#pragma unroll
      for (int kc = 0; kc < 4; ++kc) {
        bf16x8 a = *(const bf16x8*)(sb + ((kc * 64 + lhi * 16) ^ swz_r));
        A0 = __builtin_amdgcn_mfma_f32_16x16x32_bf16(a, wf[0][kc], A0, 0, 0, 0);
        A1 = __builtin_amdgcn_mfma_f32_16x16x32_bf16(a, wf[1][kc], A1, 0, 0, 0);
      }
    };
    if (nbcnt > 0) slot_mac((int)((sv >> 13) & 31u), aP0, aP1);
    if (nbcnt > 1) slot_mac((int)((sv >> 18) & 31u), aS0, aS1);
    if (nbcnt > 2) slot_mac((int)((sv >> 23) & 31u), aT0, aT1);

    if (nbcnt > 1) { aP0 += aS0; aP1 += aS1; }
    if (nbcnt > 2) { aP0 += aT0; aP1 += aT1; }

    // epilogue: relu + LDS write first (others wait on this), macc deferred
    char* dst = smem + snew * SLOT_BYTES;
    float hv0[4], hv1[4];
#pragma unroll
    for (int r = 0; r < 4; ++r) {
      const int row = lhi * 4 + r;
      hv0[r] = fmaxf(aP0[r] + bias[0], 0.f);
      hv1[r] = fmaxf(aP1[r] + bias[1], 0.f);
      const u32 wv = (u32)f2bf(hv0[r]) | ((u32)f2bf(hv1[r]) << 16);
      *(u32*)(dst + row * 256 + (wcol ^ ((row & 7) << 4))) = wv;
    }
    __syncthreads();

    const float wp = s_wp[pi];
#pragma unroll
    for (int r = 0; r < 4; ++r) {
      macc0[r] += hv0[r] * wp;
      macc1[r] += hv1[r] * wp;
    }
  }

  // ---- store per-(d,t) partial of m ------------------------------------------
#pragma unroll
  for (int r = 0; r < 4; ++r) {
    const int row = lhi * 4 + r;
    const int t = t0 + (row >> 3);
    const int brow = b0 + (row & 7);
    const int n0 = wid * 32 + l15;
    float* pp = part + (((size_t)d * 16 + t) * 128 + brow) * 128;
    pp[n0]      = macc0[r];
    pp[n0 + 16] = macc1[r];
  }
}

// ---------------------------------------------------------------------------
// Reduce 4 direction-partials + C0 -> ms (bf16).
// ---------------------------------------------------------------------------
__global__ __launch_bounds__(256) void reduce_ms_kernel(
    const float* __restrict__ part, const float* __restrict__ Pb,
    const float* __restrict__ psw,  const float* __restrict__ psb,
    u16* __restrict__ msbf)
{
  const int idx = blockIdx.x * 256 + threadIdx.x;   // 262144 total
  float c0 = psb[0];
  for (int i = 0; i < 64; ++i) c0 += Pb[i] * psw[i];
  float s = c0 + part[idx] + part[262144 + idx] + part[2 * 262144 + idx] + part[3 * 262144 + idx];
  msbf[idx] = f2bf(s);
}

// ---------------------------------------------------------------------------
// TRNN: 16 WGs = 8 b-blocks x 2 dirs. In-register p1-dot reduction during the
// scan (no global h round-trip); epilogue atomicAdd into pre-zeroed out.
// ---------------------------------------------------------------------------
__global__ __launch_bounds__(256) void trnn_kernel(
    const u16* __restrict__ msbf,
    const float* __restrict__ frs, const float* __restrict__ frsb,
    const float* __restrict__ fvs, const float* __restrict__ fvsb,
    const float* __restrict__ fbs, const float* __restrict__ fpj, const float* __restrict__ fpjb,
    const float* __restrict__ brs, const float* __restrict__ brsb,
    const float* __restrict__ bvs, const float* __restrict__ bvsb,
    const float* __restrict__ bbs, const float* __restrict__ bpj, const float* __restrict__ bpjb,
    const float* __restrict__ fp1w, const float* __restrict__ fp1b,
    const float* __restrict__ fp2w, const float* __restrict__ fp2b,
    const float* __restrict__ bp1w, const float* __restrict__ bp1b,
    const float* __restrict__ bp2w, const float* __restrict__ bp2b,
    float* __restrict__ out)
{
  __shared__ u16   hbuf[2][16][136];
  __shared__ float sredw[16][16][4];
  __shared__ float sred2[16][16];
  const int tid = threadIdx.x;
  const int lane = tid & 63, wid = tid >> 6;
  const int l15 = lane & 15, lhi = lane >> 4;
  const int dir = blockIdx.x & 1;
  const int b0 = (blockIdx.x >> 1) * 16;

  const float* rs  = dir ? brs  : frs;
  const float* rsb = dir ? brsb : frsb;
  const float* vs  = dir ? bvs  : fvs;
  const float* vsb = dir ? bvsb : fvsb;
  const float* bs  = dir ? bbs  : fbs;
  const float* w1  = dir ? bp1w : fp1w;

  // prologue: weight fragments (float4 loads)
  bf16x8 rf[2][4], vf[2][4];
  float bias[2], w1a, w1b;
#pragma unroll
  for (int nt = 0; nt < 2; ++nt) {
    const int n = wid * 32 + nt * 16 + l15;
#pragma unroll
    for (int kc = 0; kc < 4; ++kc) {
      const float* p = rs + (size_t)n * 128 + kc * 32 + lhi * 8;
      const float* q = vs + (size_t)n * 128 + kc * 32 + lhi * 8;
      float4 pa = *(const float4*)p, pb = *(const float4*)(p + 4);
      float4 qa = *(const float4*)q, qb = *(const float4*)(q + 4);
      bf16x8 a, b;
      a[0]=(short)f2bf(pa.x); a[1]=(short)f2bf(pa.y); a[2]=(short)f2bf(pa.z); a[3]=(short)f2bf(pa.w);
      a[4]=(short)f2bf(pb.x); a[5]=(short)f2bf(pb.y); a[6]=(short)f2bf(pb.z); a[7]=(short)f2bf(pb.w);
      b[0]=(short)f2bf(qa.x); b[1]=(short)f2bf(qa.y); b[2]=(short)f2bf(qa.z); b[3]=(short)f2bf(qa.w);
      b[4]=(short)f2bf(qb.x); b[5]=(short)f2bf(qb.y); b[6]=(short)f2bf(qb.z); b[7]=(short)f2bf(qb.w);
      rf[nt][kc] = a; vf[nt][kc] = b;
    }
    bias[nt] = rsb[n] + vsb[n] + bs[n];
  }
  w1a = w1[wid * 32 + l15];
  w1b = w1[wid * 32 + 16 + l15];

  for (int i = tid; i < 16 * 136; i += 256) (&hbuf[0][0][0])[i] = 0;
  __syncthreads();

  int cur = 0;
  for (int tt2 = 0; tt2 < 16; ++tt2) {
    const int tt = dir ? (15 - tt2) : tt2;
    // independent acc pairs: ma@rf (no dep) and ha@vf (dep on prev step)
    f32x4 am0 = {0.f,0.f,0.f,0.f}, am1 = {0.f,0.f,0.f,0.f};
    f32x4 ah0 = {0.f,0.f,0.f,0.f}, ah1 = {0.f,0.f,0.f,0.f};
#pragma unroll
    for (int kc = 0; kc < 4; ++kc) {
      bf16x8 ma = *(const bf16x8*)(msbf + ((size_t)tt * 128 + b0 + l15) * 128 + kc * 32 + lhi * 8);
      bf16x8 ha = *(const bf16x8*)(&hbuf[cur][l15][kc * 32 + lhi * 8]);
      am0 = __builtin_amdgcn_mfma_f32_16x16x32_bf16(ma, rf[0][kc], am0, 0, 0, 0);
      ah0 = __builtin_amdgcn_mfma_f32_16x16x32_bf16(ha, vf[0][kc], ah0, 0, 0, 0);
      am1 = __builtin_amdgcn_mfma_f32_16x16x32_bf16(ma, rf[1][kc], am1, 0, 0, 0);
      ah1 = __builtin_amdgcn_mfma_f32_16x16x32_bf16(ha, vf[1][kc], ah1, 0, 0, 0);
    }
    float pr[4];
#pragma unroll
    for (int r = 0; r < 4; ++r) {
      const int row = lhi * 4 + r;
      float h0 = fmaxf(am0[r] + ah0[r] + bias[0], 0.f);
      float h1 = fmaxf(am1[r] + ah1[r] + bias[1], 0.f);
      hbuf[cur ^ 1][row][wid * 32 + l15]      = f2bf(h0);
      hbuf[cur ^ 1][row][wid * 32 + 16 + l15] = f2bf(h1);
      pr[r] = h0 * w1a + h1 * w1b;
    }
    // p1-dot reduction over the 16-lane l15 group (off critical path: after writes)
#pragma unroll
    for (int r = 0; r < 4; ++r) {
      float p = pr[r];
      p += __shfl_xor(p, 1);
      p += __shfl_xor(p, 2);
      p += __shfl_xor(p, 4);
      p += __shfl_xor(p, 8);
      if (l15 == 0) sredw[tt2][lhi * 4 + r][wid] = p;
    }
    __syncthreads();
    cur ^= 1;
  }

  // combine wave partials
  {
    const int tq = tid >> 4, bq = tid & 15;
    float s = sredw[tq][bq][0] + sredw[tq][bq][1] + sredw[tq][bq][2] + sredw[tq][bq][3];
    sred2[tq][bq] = s;
  }
  __syncthreads();

  if (tid < 48) {
    const int b = tid / 3, c = tid % 3;
    const float* p1w = dir ? bp1w : fp1w;
    const float* p1b = dir ? bp1b : fp1b;
    const float* p2w = dir ? bp2w : fp2w;
    const float* p2b = dir ? bp2b : fp2b;
    const float* pj  = dir ? bpj  : fpj;
    const float* pjb = dir ? bpjb : fpjb;
    float val = 0.f;
    // constant term (dir-specific, added once per dir)
    float S1 = 0.f;
    for (int h = 0; h < 128; ++h) S1 += p1w[h];
    float C = p2b[c];
    for (int p = 0; p < 8; ++p) C += (pjb[p] * S1 + p1b[0]) * p2w[c * 8 + p];
    val += C;
    for (int t2 = 0; t2 < 16; ++t2) {
      float g = 0.f;
      for (int p = 0; p < 8; ++p) g += p2w[c * 8 + p] * pj[p * 16 + t2];
      val += sred2[t2][b] * g;
    }
    atomicAdd(out + (b0 + b) * 3 + c, val);
  }
}

extern "C" void kernel_launch(void* const* d_in, const int* in_sizes, int n_in,
                              void* d_out, int out_size, void* d_ws, size_t ws_size,
                              hipStream_t stream)
{
  (void)in_sizes; (void)n_in; (void)ws_size;
  const float* x    = (const float*)d_in[0];
  const float* Uw   = (const float*)d_in[3];
  const float* Ub   = (const float*)d_in[4];
  const float* Ww   = (const float*)d_in[5];
  const float* Wb   = (const float*)d_in[6];
  const float* spbs = (const float*)d_in[7];
  const float* Pw   = (const float*)d_in[8];
  const float* Pb   = (const float*)d_in[9];
  const float* psw  = (const float*)d_in[10];
  const float* psb  = (const float*)d_in[11];
  const float* frs  = (const float*)d_in[12];
  const float* frsb = (const float*)d_in[13];
  const float* fvs  = (const float*)d_in[14];
  const float* fvsb = (const float*)d_in[15];
  const float* fbs  = (const float*)d_in[16];
  const float* fpj  = (const float*)d_in[17];
  const float* fpjb = (const float*)d_in[18];
  const float* brs  = (const float*)d_in[19];
  const float* brsb = (const float*)d_in[20];
  const float* bvs  = (const float*)d_in[21];
  const float* bvsb = (const float*)d_in[22];
  const float* bbs  = (const float*)d_in[23];
  const float* bpj  = (const float*)d_in[24];
  const float* bpjb = (const float*)d_in[25];
  const float* fp1w = (const float*)d_in[26];
  const float* fp1b = (const float*)d_in[27];
  const float* fp2w = (const float*)d_in[28];
  const float* fp2b = (const float*)d_in[29];
  const float* bp1w = (const float*)d_in[30];
  const float* bp1b = (const float*)d_in[31];
  const float* bp2w = (const float*)d_in[32];
  const float* bp2b = (const float*)d_in[33];

  char* ws = (char*)d_ws;
  float* part = (float*)(ws);              // 4 MiB [4][16][128][128] f32
  u16*   msbf = (u16*)(ws + 4194304);      // 512 KiB [16][128][128] bf16

  hipFuncSetAttribute((const void*)srnn_kernel,
                      hipFuncAttributeMaxDynamicSharedMemorySize, SMEM_TOTAL);

  hipMemsetAsync(d_out, 0, (size_t)out_size * sizeof(float), stream);

  srnn_kernel<<<dim3(512), dim3(256), SMEM_TOTAL, stream>>>(
      x, Uw, Ub, Ww, Wb, spbs, Pw, psw, part);
  reduce_ms_kernel<<<dim3(1024), dim3(256), 0, stream>>>(part, Pb, psw, psb, msbf);
  trnn_kernel<<<dim3(16), dim3(256), 0, stream>>>(msbf,
      frs, frsb, fvs, fvsb, fbs, fpj, fpjb,
      brs, brsb, bvs, bvsb, bbs, bpj, bpjb,
      fp1w, fp1b, fp2w, fp2b, bp1w, bp1b, bp2w, bp2b,
      (float*)d_out);
}

// Round 4
// 89.670 us; speedup vs baseline: 1.7496x; 1.1644x over previous
//
#include <hip/hip_runtime.h>

typedef unsigned short u16;
typedef unsigned int   u32;

using bf16x8 = __attribute__((ext_vector_type(8))) short;
using f32x4  = __attribute__((ext_vector_type(4))) float;
using u32x4  = __attribute__((ext_vector_type(4))) unsigned;

__device__ __forceinline__ u32 cvtpk(float lo, float hi) {
  u32 r;
  asm("v_cvt_pk_bf16_f32 %0, %1, %2" : "=v"(r) : "v"(lo), "v"(hi));
  return r;
}
__device__ __forceinline__ bf16x8 pack8(float f0,float f1,float f2,float f3,
                                        float f4,float f5,float f6,float f7) {
  u32x4 t; t[0]=cvtpk(f0,f1); t[1]=cvtpk(f2,f3); t[2]=cvtpk(f4,f5); t[3]=cvtpk(f6,f7);
  return __builtin_bit_cast(bf16x8, t);
}
__device__ __forceinline__ u16 f2bf(float f) {
  u32 u = __float_as_uint(f);
  u32 r = u + 0x7FFFu + ((u >> 16) & 1u);
  return (u16)(r >> 16);
}

// ---------------------------------------------------------------------------
// Compile-time level-batched schedule. Steps sorted by DAG level; barrier only
// at level boundaries (plus on-demand splits when slot pressure hits the cap).
// ---------------------------------------------------------------------------
struct Sched {
  unsigned v[4][64];        // e:0-5 | slot:6-10 (31=no write) | nc:11-12 | s1:13-17 | s2:18-22 | s3:23-27 | bar:28
  unsigned char opi[4][64]; // original step index (for wproj)
  int nslot;
};

constexpr int cCOOR[62][2] = {
  {1,4},{1,5},{1,6},{2,4},{2,6},
  {3,1},{3,2},{3,3},{3,4},{3,5},{3,6},{3,7},{3,8},{3,9},
  {4,1},{4,2},{4,3},{4,4},{4,5},{4,6},{4,7},{4,8},{4,9},
  {5,1},{5,2},{5,3},{5,4},{5,5},{5,6},{5,7},{5,8},{5,9},
  {6,1},{6,2},{6,3},{6,4},{6,5},{6,6},{6,7},{6,8},{6,9},
  {7,1},{7,2},{7,3},{7,4},{7,5},{7,6},{7,7},{7,8},{7,9},
  {8,2},{8,3},{8,4},{8,5},{8,6},{8,7},{8,8},
  {9,3},{9,4},{9,5},{9,6},{9,7}};

constexpr int cDIRS[4][62] = {
  {1,2,3,4,5,6,7,8,9,10,11,12,13,14,15,16,17,18,19,20,21,22,23,24,25,26,27,28,29,30,
   31,32,33,34,35,36,37,38,39,40,41,42,43,44,45,46,47,48,49,50,
   58,52,53,54,55,56,62,60,61,51,57,59},
  {59,57,51,61,60,62,56,55,54,53,52,58,50,41,32,23,14,49,40,31,22,13,48,39,30,21,12,
   47,38,29,20,11,46,37,28,19,10,45,36,27,18,9,44,35,26,17,8,43,34,25,16,7,42,33,24,
   15,6,5,4,3,2,1},
  {59,57,51,61,60,62,56,55,54,53,52,58,50,49,48,47,46,45,44,43,42,41,40,39,38,37,36,
   35,34,33,32,31,30,29,28,27,26,25,24,23,22,21,20,19,18,17,16,15,14,13,12,11,10,9,
   8,7,6,5,4,3,2,1},
  {1,2,3,4,5,6,15,24,33,42,7,16,25,34,43,8,17,26,35,44,9,18,27,36,45,10,19,28,37,46,
   11,20,29,38,47,12,21,30,39,48,13,22,31,40,49,14,23,32,41,50,
   58,52,53,54,55,56,62,60,61,51,57,59}};

constexpr int cOFFS[4][3][2] = {
  {{0,-1},{-1,-1},{-1,0}},
  {{0, 1},{-1, 0},{-1,1}},
  {{0,-1},{ 1,-1},{ 1,0}},
  {{0,-1},{-1,-1},{-1,0}}};

constexpr Sched make_sched() {
  Sched S{};
  int nslot_all = 0;
  for (int d = 0; d < 4; ++d) {
    int pos_of[63] = {};
    for (int p = 0; p < 62; ++p) pos_of[cDIRS[d][p]] = p;
    int nb[62][3] = {}; int nc[62] = {}; int rdcnt[62] = {};
    for (int p = 0; p < 62; ++p) {
      const int e = cDIRS[d][p];
      const int ci = cCOOR[e-1][0], cj = cCOOR[e-1][1];
      for (int o = 0; o < 3; ++o) {
        const int ni = ci + cOFFS[d][o][0], nj = cj + cOFFS[d][o][1];
        int q = 0;
        for (int k2 = 0; k2 < 62; ++k2)
          if (cCOOR[k2][0]==ni && cCOOR[k2][1]==nj) { q = k2+1; break; }
        if (q) { const int qp = pos_of[q];
          if (qp < p) { nb[p][nc[p]] = qp; nc[p] = nc[p]+1; rdcnt[qp] = rdcnt[qp]+1; } }
      }
    }
    int lvl[62] = {};
    for (int p = 0; p < 62; ++p) {
      int m = 0;
      for (int o = 0; o < nc[p]; ++o) if (lvl[nb[p][o]] > m) m = lvl[nb[p][o]];
      lvl[p] = m + 1;
    }
    int ord[62] = {}; int k = 0;
    for (int L = 1; L <= 62; ++L)
      for (int p = 0; p < 62; ++p) if (lvl[p] == L) { ord[k] = p; k = k+1; }
    // slot allocation with sub-phases
    int slotof[62] = {};
    int rl[20]; int lr[20];
    for (int s = 0; s < 20; ++s) { rl[s] = 0; lr[s] = -1; }
    int nslot = 0, cur_sub = 0;
    int barafter[62] = {};
    int prev_lvl = lvl[ord[0]];
    for (int kk = 0; kk < 62; ++kk) {
      const int p = ord[kk];
      if (lvl[p] != prev_lvl) { barafter[kk-1] = 1; cur_sub = cur_sub+1; prev_lvl = lvl[p]; }
      for (int o = 0; o < nc[p]; ++o) {   // mark reads (decrement once)
        const int s = slotof[nb[p][o]];
        rl[s] = rl[s]-1;
        if (cur_sub > lr[s]) lr[s] = cur_sub;
      }
      int myslot = 31;
      if (rdcnt[p] > 0) {
        int found = -1;
        for (int s = 0; s < nslot; ++s)
          if (rl[s] == 0 && lr[s] < cur_sub) { found = s; break; }
        if (found < 0 && nslot < 19) { found = nslot; nslot = nslot+1; }
        if (found < 0) {
          barafter[kk-1] = 1; cur_sub = cur_sub+1;    // split phase
          for (int o = 0; o < nc[p]; ++o) {           // protect own reads
            const int s = slotof[nb[p][o]];
            if (cur_sub > lr[s]) lr[s] = cur_sub;
          }
          for (int s = 0; s < nslot; ++s)
            if (rl[s] == 0 && lr[s] < cur_sub) { found = s; break; }
        }
        if (found < 0 && nslot < 20) { found = nslot; nslot = nslot+1; }
        if (found < 0) found = 0; // unreachable by liveness analysis (<=19)
        myslot = found;
        rl[myslot] = rdcnt[p];
        lr[myslot] = -1;
        slotof[p] = myslot;
      }
      S.opi[d][kk] = (unsigned char)p;
      S.v[d][kk] = (unsigned)(cDIRS[d][p]-1)
                 | ((unsigned)myslot << 6)
                 | ((unsigned)nc[p] << 11)
                 | ((unsigned)(nc[p]>0 ? slotof[nb[p][0]] : 0) << 13)
                 | ((unsigned)(nc[p]>1 ? slotof[nb[p][1]] : 0) << 18)
                 | ((unsigned)(nc[p]>2 ? slotof[nb[p][2]] : 0) << 23);
    }
    for (int kk = 0; kk < 62; ++kk) if (barafter[kk]) S.v[d][kk] |= (1u << 28);
    if (nslot > nslot_all) nslot_all = nslot;
  }
  S.nslot = nslot_all;
  return S;
}

constexpr Sched g_sched = make_sched();
static_assert(g_sched.nslot >= 8 && g_sched.nslot <= 20, "slot pressure out of range");
__constant__ Sched c_sched = make_sched();

constexpr int POOL_B     = g_sched.nslot * 4096;   // h slots [16 rows][128] bf16, swizzled
constexpr int WP_OFF     = POOL_B;                 // wproj[62] f32
constexpr int SRNN_SMEM  = POOL_B + 256;

// ---------------------------------------------------------------------------
// SRNN: one WG per (t-pair, d, b-block of 8). Level-batched scan: barrier only
// at (sub-)phase boundaries (~15 instead of 62). x loaded global->reg per step,
// consumed by the last MFMA of the chain. bias folded into acc init.
// ---------------------------------------------------------------------------
__global__ __launch_bounds__(256, 2) void srnn_kernel(
    const float* __restrict__ x,    const float* __restrict__ Uw,
    const float* __restrict__ Ub,   const float* __restrict__ Ww,
    const float* __restrict__ Wb,   const float* __restrict__ spbs,
    const float* __restrict__ Pw,   const float* __restrict__ psw,
    float* __restrict__ part)
{
  extern __shared__ __align__(16) char smem[];
  const int tid  = threadIdx.x;
  const int lane = tid & 63, wid = tid >> 6;
  const int l15  = lane & 15, lhi = lane >> 4;
  const int bx = blockIdx.x;
  const int bb = bx & 15, d = (bx >> 4) & 3, tp = bx >> 6;
  const int b0 = bb * 8, t0 = tp * 2;

  float* s_wp = (float*)(smem + WP_OFF);

  // ---- prologue: wproj ------------------------------------------------------
  if (tid < 62) {
    const int opi = c_sched.opi[d][tid];
    float acc = 0.f;
    for (int q = 0; q < 16; ++q) acc += Pw[(d * 16 + q) * 62 + opi] * psw[d * 16 + q];
    s_wp[tid] = acc;
  }

  // W B-fragments, k-interleaved (physical q=2i+j <-> logical k=i+16j)
  bf16x8 wf[2][4];
  float bias[2];
#pragma unroll
  for (int nt = 0; nt < 2; ++nt) {
    const int n = wid * 32 + nt * 16 + l15;
    const float* wr = Ww + (size_t)(d * 128 + n) * 128;
#pragma unroll
    for (int kc = 0; kc < 4; ++kc) {
      float4 lo = *(const float4*)(wr + kc * 32 + lhi * 4);
      float4 hi = *(const float4*)(wr + kc * 32 + lhi * 4 + 16);
      wf[nt][kc] = pack8(lo.x, hi.x, lo.y, hi.y, lo.z, hi.z, lo.w, hi.w);
    }
    bias[nt] = Ub[d * 128 + n] + Wb[d * 128 + n] + spbs[d * 128 + n];
  }

  // Uw B-fragments: only lhi==0 lanes carry real k (c=0..4), rest zero.
  float u0a=0,u1a=0,u2a=0,u3a=0,u4a=0, u0b=0,u1b=0,u2b=0,u3b=0,u4b=0;
  if (lhi == 0) {
    const float* ua = Uw + (d * 128 + wid * 32 + l15) * 5;
    const float* ub = Uw + (d * 128 + wid * 32 + 16 + l15) * 5;
    u0a=ua[0]; u1a=ua[1]; u2a=ua[2]; u3a=ua[3]; u4a=ua[4];
    u0b=ub[0]; u1b=ub[1]; u2b=ub[2]; u3b=ub[3]; u4b=ub[4];
  }
  const bf16x8 uwf0 = pack8(u0a,u1a,u2a,u3a,u4a,0.f,0.f,0.f);
  const bf16x8 uwf1 = pack8(u0b,u1b,u2b,u3b,u4b,0.f,0.f,0.f);

  __syncthreads();   // s_wp visible; slots written before any read (allocator)

  const float* xlane = x + (size_t)((b0 + (l15 & 7)) * 16 + (t0 + (l15 >> 3))) * 310;
  const int swz_r = ((l15 & 7) << 4);
  const int wcol  = wid * 64 + l15 * 4;
  const unsigned* scv = c_sched.v[d];

  f32x4 macc0 = {0.f,0.f,0.f,0.f}, macc1 = {0.f,0.f,0.f,0.f};

  auto do_step = [&](unsigned sv, int kidx, float c0, float c1, float c2, float c3, float c4) {
    f32x4 a0 = {bias[0], bias[0], bias[0], bias[0]};
    f32x4 a1 = {bias[1], bias[1], bias[1], bias[1]};
    const int nbc = (int)((sv >> 11) & 3u);
    auto slot_mac = [&](int sl) {
      const char* sb = smem + sl * 4096 + l15 * 256;
#pragma unroll
      for (int kc = 0; kc < 4; ++kc) {
        bf16x8 a = *(const bf16x8*)(sb + ((kc * 64 + lhi * 16) ^ swz_r));
        a0 = __builtin_amdgcn_mfma_f32_16x16x32_bf16(a, wf[0][kc], a0, 0, 0, 0);
        a1 = __builtin_amdgcn_mfma_f32_16x16x32_bf16(a, wf[1][kc], a1, 0, 0, 0);
      }
    };
    if (nbc > 0) slot_mac((int)((sv >> 13) & 31u));
    if (nbc > 1) slot_mac((int)((sv >> 18) & 31u));
    if (nbc > 2) slot_mac((int)((sv >> 23) & 31u));
    // x term last: global-load latency hidden behind the slot MFMAs
    bf16x8 xa = pack8(c0, c1, c2, c3, c4, 0.f, 0.f, 0.f);
    a0 = __builtin_amdgcn_mfma_f32_16x16x32_bf16(xa, uwf0, a0, 0, 0, 0);
    a1 = __builtin_amdgcn_mfma_f32_16x16x32_bf16(xa, uwf1, a1, 0, 0, 0);

    const int snew = (int)((sv >> 6) & 31u);
    const float wp = s_wp[kidx];
    float h0r[4], h1r[4];
#pragma unroll
    for (int r = 0; r < 4; ++r) { h0r[r] = fmaxf(a0[r], 0.f); h1r[r] = fmaxf(a1[r], 0.f); }
    if (snew != 31) {
      char* dst = smem + snew * 4096;
#pragma unroll
      for (int r = 0; r < 4; ++r) {
        const int row = lhi * 4 + r;
        *(u32*)(dst + row * 256 + (wcol ^ ((row & 7) << 4))) = cvtpk(h0r[r], h1r[r]);
      }
    }
#pragma unroll
    for (int r = 0; r < 4; ++r) { macc0[r] += h0r[r] * wp; macc1[r] += h1r[r] * wp; }
  };

  for (int pp = 0; pp < 31; ++pp) {
    const unsigned svA = scv[2 * pp];
    const unsigned svB = scv[2 * pp + 1];
    float a0=0,a1=0,a2=0,a3=0,a4=0, b0f=0,b1f=0,b2f=0,b3f=0,b4f=0;
    if (lhi == 0) {
      const float* pA = xlane + (svA & 63u) * 5;
      const float* pB = xlane + (svB & 63u) * 5;
      a0=pA[0]; a1=pA[1]; a2=pA[2]; a3=pA[3]; a4=pA[4];
      b0f=pB[0]; b1f=pB[1]; b2f=pB[2]; b3f=pB[3]; b4f=pB[4];
    }
    do_step(svA, 2 * pp, a0, a1, a2, a3, a4);
    if (svA & (1u << 28)) __syncthreads();
    do_step(svB, 2 * pp + 1, b0f, b1f, b2f, b3f, b4f);
    if (svB & (1u << 28)) __syncthreads();
  }

  // ---- store per-(d,t) partial of m ------------------------------------------
#pragma unroll
  for (int r = 0; r < 4; ++r) {
    const int row = lhi * 4 + r;
    const int t = t0 + (row >> 3);
    const int brow = b0 + (row & 7);
    const int n0 = wid * 32 + l15;
    float* pp2 = part + (((size_t)d * 16 + t) * 128 + brow) * 128;
    pp2[n0]      = macc0[r];
    pp2[n0 + 16] = macc1[r];
  }
}

// ---------------------------------------------------------------------------
// TRNN: 16 WGs = 8 b-blocks x 2 dirs. Prologue folds the 4-dir reduction of
// part into an LDS ms slice (swizzled). Scan reads ms/h from LDS; in-register
// p1-dot reduction; atomicAdd into pre-zeroed out.
// ---------------------------------------------------------------------------
constexpr int MS_OFF = 0;                 // [16 t][16 b][256 B] swizzled bf16
constexpr int HB_OFF = 65536;             // hbuf [2][16][136] u16 = 8704
constexpr int SW_OFF = HB_OFF + 8704;     // sredw [16][16][4] f32 = 4096
constexpr int S2_OFF = SW_OFF + 4096;     // sred2 [16][16] f32 = 1024
constexpr int TRNN_SMEM = S2_OFF + 1024;  // 79360

__global__ __launch_bounds__(256) void trnn_kernel(
    const float* __restrict__ part, const float* __restrict__ Pb,
    const float* __restrict__ psw,  const float* __restrict__ psb,
    const float* __restrict__ frs, const float* __restrict__ frsb,
    const float* __restrict__ fvs, const float* __restrict__ fvsb,
    const float* __restrict__ fbs, const float* __restrict__ fpj, const float* __restrict__ fpjb,
    const float* __restrict__ brs, const float* __restrict__ brsb,
    const float* __restrict__ bvs, const float* __restrict__ bvsb,
    const float* __restrict__ bbs, const float* __restrict__ bpj, const float* __restrict__ bpjb,
    const float* __restrict__ fp1w, const float* __restrict__ fp1b,
    const float* __restrict__ fp2w, const float* __restrict__ fp2b,
    const float* __restrict__ bp1w, const float* __restrict__ bp1b,
    const float* __restrict__ bp2w, const float* __restrict__ bp2b,
    float* __restrict__ out)
{
  extern __shared__ __align__(16) char smem[];
  const int tid = threadIdx.x;
  const int lane = tid & 63, wid = tid >> 6;
  const int l15 = lane & 15, lhi = lane >> 4;
  const int dir = blockIdx.x & 1;
  const int b0 = (blockIdx.x >> 1) * 16;

  const float* rs  = dir ? brs  : frs;
  const float* rsb = dir ? brsb : frsb;
  const float* vs  = dir ? bvs  : fvs;
  const float* vsb = dir ? bvsb : fvsb;
  const float* bs  = dir ? bbs  : fbs;
  const float* w1  = dir ? bp1w : fp1w;

  // ---- prologue A: ms slice = sum_d part + C0 -> LDS (swizzled) --------------
  {
    const int tq = tid >> 4, bq = tid & 15;
    float c0 = psb[0];
#pragma unroll
    for (int i = 0; i < 16; ++i) {
      float4 pb4 = *(const float4*)(Pb + i * 4);
      float4 pw4 = *(const float4*)(psw + i * 4);
      c0 += pb4.x*pw4.x + pb4.y*pw4.y + pb4.z*pw4.z + pb4.w*pw4.w;
    }
    const size_t base = ((size_t)tq * 128 + b0 + bq) * 128;
    const float* p0 = part + base;
    const float* p1 = part + base + 262144;
    const float* p2 = part + base + 2 * 262144;
    const float* p3 = part + base + 3 * 262144;
    char* mrow = smem + MS_OFF + (tq * 16 + bq) * 256;
    const int sz = (bq & 7) << 4;
    for (int h4 = 0; h4 < 32; ++h4) {
      float4 v0 = *(const float4*)(p0 + h4 * 4);
      float4 v1 = *(const float4*)(p1 + h4 * 4);
      float4 v2 = *(const float4*)(p2 + h4 * 4);
      float4 v3 = *(const float4*)(p3 + h4 * 4);
      float s0 = v0.x + v1.x + v2.x + v3.x + c0;
      float s1 = v0.y + v1.y + v2.y + v3.y + c0;
      float s2 = v0.z + v1.z + v2.z + v3.z + c0;
      float s3 = v0.w + v1.w + v2.w + v3.w + c0;
      *(u32*)(mrow + ((h4 * 8) ^ sz))     = cvtpk(s0, s1);
      *(u32*)(mrow + ((h4 * 8 + 4) ^ sz)) = cvtpk(s2, s3);
    }
  }

  // ---- prologue B: weight fragments ------------------------------------------
  bf16x8 rf[2][4], vf[2][4];
  float bias[2], w1a, w1b;
#pragma unroll
  for (int nt = 0; nt < 2; ++nt) {
    const int n = wid * 32 + nt * 16 + l15;
#pragma unroll
    for (int kc = 0; kc < 4; ++kc) {
      // rf: natural k order (ms stored naturally within 16B chunks)
      float4 ra = *(const float4*)(rs + (size_t)n * 128 + kc * 32 + lhi * 8);
      float4 rb = *(const float4*)(rs + (size_t)n * 128 + kc * 32 + lhi * 8 + 4);
      rf[nt][kc] = pack8(ra.x, ra.y, ra.z, ra.w, rb.x, rb.y, rb.z, rb.w);
      // vf: k-interleaved (matches packed u32 h-writes)
      float4 lo = *(const float4*)(vs + (size_t)n * 128 + kc * 32 + lhi * 4);
      float4 hi = *(const float4*)(vs + (size_t)n * 128 + kc * 32 + lhi * 4 + 16);
      vf[nt][kc] = pack8(lo.x, hi.x, lo.y, hi.y, lo.z, hi.z, lo.w, hi.w);
    }
    bias[nt] = rsb[n] + vsb[n] + bs[n];
  }
  w1a = w1[wid * 32 + l15];
  w1b = w1[wid * 32 + 16 + l15];

  for (int i = tid; i < 2176; i += 256) *(u16*)(smem + HB_OFF + i * 2) = 0;
  __syncthreads();

  float* sredw = (float*)(smem + SW_OFF);
  float* sred2 = (float*)(smem + S2_OFF);

  int cur = 0;
  for (int tt2 = 0; tt2 < 16; ++tt2) {
    const int tt = dir ? (15 - tt2) : tt2;
    f32x4 am0 = {bias[0],bias[0],bias[0],bias[0]};
    f32x4 am1 = {bias[1],bias[1],bias[1],bias[1]};
    f32x4 ah0 = {0.f,0.f,0.f,0.f}, ah1 = {0.f,0.f,0.f,0.f};
    const char* msrow = smem + MS_OFF + (tt * 16 + l15) * 256;
    const int msz = (l15 & 7) << 4;
#pragma unroll
    for (int kc = 0; kc < 4; ++kc) {
      bf16x8 ma = *(const bf16x8*)(msrow + ((kc * 64 + lhi * 16) ^ msz));
      bf16x8 ha = *(const bf16x8*)(smem + HB_OFF + (cur * 16 + l15) * 272 + kc * 64 + lhi * 16);
      am0 = __builtin_amdgcn_mfma_f32_16x16x32_bf16(ma, rf[0][kc], am0, 0, 0, 0);
      ah0 = __builtin_amdgcn_mfma_f32_16x16x32_bf16(ha, vf[0][kc], ah0, 0, 0, 0);
      am1 = __builtin_amdgcn_mfma_f32_16x16x32_bf16(ma, rf[1][kc], am1, 0, 0, 0);
      ah1 = __builtin_amdgcn_mfma_f32_16x16x32_bf16(ha, vf[1][kc], ah1, 0, 0, 0);
    }
    float pr[4];
#pragma unroll
    for (int r = 0; r < 4; ++r) {
      const int row = lhi * 4 + r;
      float h0 = fmaxf(am0[r] + ah0[r], 0.f);
      float h1 = fmaxf(am1[r] + ah1[r], 0.f);
      *(u32*)(smem + HB_OFF + ((cur ^ 1) * 16 + row) * 272 + wid * 64 + l15 * 4) = cvtpk(h0, h1);
      pr[r] = h0 * w1a + h1 * w1b;
    }
#pragma unroll
    for (int r = 0; r < 4; ++r) {
      float p = pr[r];
      p += __shfl_xor(p, 1);
      p += __shfl_xor(p, 2);
      p += __shfl_xor(p, 4);
      p += __shfl_xor(p, 8);
      if (l15 == 0) sredw[(tt2 * 16 + lhi * 4 + r) * 4 + wid] = p;
    }
    __syncthreads();
    cur ^= 1;
  }

  {
    const int tq = tid >> 4, bq = tid & 15;
    const float* sw = sredw + (tq * 16 + bq) * 4;
    sred2[tq * 16 + bq] = sw[0] + sw[1] + sw[2] + sw[3];
  }
  __syncthreads();

  if (tid < 48) {
    const int b = tid / 3, c = tid % 3;
    const float* p1w = dir ? bp1w : fp1w;
    const float* p1b = dir ? bp1b : fp1b;
    const float* p2w = dir ? bp2w : fp2w;
    const float* p2b = dir ? bp2b : fp2b;
    const float* pj  = dir ? bpj  : fpj;
    const float* pjb = dir ? bpjb : fpjb;
    float S1 = 0.f;
    for (int h = 0; h < 128; ++h) S1 += p1w[h];
    float val = p2b[c];
    for (int p = 0; p < 8; ++p) val += (pjb[p] * S1 + p1b[0]) * p2w[c * 8 + p];
    for (int t2 = 0; t2 < 16; ++t2) {
      float g = 0.f;
      for (int p = 0; p < 8; ++p) g += p2w[c * 8 + p] * pj[p * 16 + t2];
      val += sred2[t2 * 16 + b] * g;
    }
    atomicAdd(out + (b0 + b) * 3 + c, val);
  }
}

extern "C" void kernel_launch(void* const* d_in, const int* in_sizes, int n_in,
                              void* d_out, int out_size, void* d_ws, size_t ws_size,
                              hipStream_t stream)
{
  (void)in_sizes; (void)n_in; (void)ws_size;
  const float* x    = (const float*)d_in[0];
  const float* Uw   = (const float*)d_in[3];
  const float* Ub   = (const float*)d_in[4];
  const float* Ww   = (const float*)d_in[5];
  const float* Wb   = (const float*)d_in[6];
  const float* spbs = (const float*)d_in[7];
  const float* Pw   = (const float*)d_in[8];
  const float* Pb   = (const float*)d_in[9];
  const float* psw  = (const float*)d_in[10];
  const float* psb  = (const float*)d_in[11];
  const float* frs  = (const float*)d_in[12];
  const float* frsb = (const float*)d_in[13];
  const float* fvs  = (const float*)d_in[14];
  const float* fvsb = (const float*)d_in[15];
  const float* fbs  = (const float*)d_in[16];
  const float* fpj  = (const float*)d_in[17];
  const float* fpjb = (const float*)d_in[18];
  const float* brs  = (const float*)d_in[19];
  const float* brsb = (const float*)d_in[20];
  const float* bvs  = (const float*)d_in[21];
  const float* bvsb = (const float*)d_in[22];
  const float* bbs  = (const float*)d_in[23];
  const float* bpj  = (const float*)d_in[24];
  const float* bpjb = (const float*)d_in[25];
  const float* fp1w = (const float*)d_in[26];
  const float* fp1b = (const float*)d_in[27];
  const float* fp2w = (const float*)d_in[28];
  const float* fp2b = (const float*)d_in[29];
  const float* bp1w = (const float*)d_in[30];
  const float* bp1b = (const float*)d_in[31];
  const float* bp2w = (const float*)d_in[32];
  const float* bp2b = (const float*)d_in[33];

  float* part = (float*)d_ws;   // 4 MiB [4][16][128][128] f32

  hipFuncSetAttribute((const void*)srnn_kernel,
                      hipFuncAttributeMaxDynamicSharedMemorySize, SRNN_SMEM);
  hipFuncSetAttribute((const void*)trnn_kernel,
                      hipFuncAttributeMaxDynamicSharedMemorySize, TRNN_SMEM);

  hipMemsetAsync(d_out, 0, (size_t)out_size * sizeof(float), stream);

  srnn_kernel<<<dim3(512), dim3(256), SRNN_SMEM, stream>>>(
      x, Uw, Ub, Ww, Wb, spbs, Pw, psw, part);
  trnn_kernel<<<dim3(16), dim3(256), TRNN_SMEM, stream>>>(part, Pb, psw, psb,
      frs, frsb, fvs, fvsb, fbs, fpj, fpjb,
      brs, brsb, bvs, bvsb, bbs, bpj, bpjb,
      fp1w, fp1b, fp2w, fp2b, bp1w, bp1b, bp2w, bp2b,
      (float*)d_out);
}

// Round 5
// 76.307 us; speedup vs baseline: 2.0561x; 1.1751x over previous
//
#include <hip/hip_runtime.h>
#include <utility>

typedef unsigned short u16;
typedef unsigned int   u32;

using bf16x8 = __attribute__((ext_vector_type(8))) short;
using f32x4  = __attribute__((ext_vector_type(4))) float;
using u32x4  = __attribute__((ext_vector_type(4))) unsigned;

__device__ __forceinline__ u32 cvtpk(float lo, float hi) {
  u32 r;
  asm("v_cvt_pk_bf16_f32 %0, %1, %2" : "=v"(r) : "v"(lo), "v"(hi));
  return r;
}
__device__ __forceinline__ bf16x8 pack8(float f0,float f1,float f2,float f3,
                                        float f4,float f5,float f6,float f7) {
  u32x4 t; t[0]=cvtpk(f0,f1); t[1]=cvtpk(f2,f3); t[2]=cvtpk(f4,f5); t[3]=cvtpk(f6,f7);
  return __builtin_bit_cast(bf16x8, t);
}
__device__ __forceinline__ u16 f2bf(float f) {
  u32 u = __float_as_uint(f);
  u32 r = u + 0x7FFFu + ((u >> 16) & 1u);
  return (u16)(r >> 16);
}

// ---------------------------------------------------------------------------
// Compile-time level-batched schedule (identical allocator to R4 - proven).
// ---------------------------------------------------------------------------
struct Sched {
  unsigned v[4][64];        // e:0-5 | slot:6-10 (31=none) | nc:11-12 | s1:13-17 | s2:18-22 | s3:23-27 | bar:28
  unsigned char opi[4][64];
  int nslot;
};

constexpr int cCOOR[62][2] = {
  {1,4},{1,5},{1,6},{2,4},{2,6},
  {3,1},{3,2},{3,3},{3,4},{3,5},{3,6},{3,7},{3,8},{3,9},
  {4,1},{4,2},{4,3},{4,4},{4,5},{4,6},{4,7},{4,8},{4,9},
  {5,1},{5,2},{5,3},{5,4},{5,5},{5,6},{5,7},{5,8},{5,9},
  {6,1},{6,2},{6,3},{6,4},{6,5},{6,6},{6,7},{6,8},{6,9},
  {7,1},{7,2},{7,3},{7,4},{7,5},{7,6},{7,7},{7,8},{7,9},
  {8,2},{8,3},{8,4},{8,5},{8,6},{8,7},{8,8},
  {9,3},{9,4},{9,5},{9,6},{9,7}};

constexpr int cDIRS[4][62] = {
  {1,2,3,4,5,6,7,8,9,10,11,12,13,14,15,16,17,18,19,20,21,22,23,24,25,26,27,28,29,30,
   31,32,33,34,35,36,37,38,39,40,41,42,43,44,45,46,47,48,49,50,
   58,52,53,54,55,56,62,60,61,51,57,59},
  {59,57,51,61,60,62,56,55,54,53,52,58,50,41,32,23,14,49,40,31,22,13,48,39,30,21,12,
   47,38,29,20,11,46,37,28,19,10,45,36,27,18,9,44,35,26,17,8,43,34,25,16,7,42,33,24,
   15,6,5,4,3,2,1},
  {59,57,51,61,60,62,56,55,54,53,52,58,50,49,48,47,46,45,44,43,42,41,40,39,38,37,36,
   35,34,33,32,31,30,29,28,27,26,25,24,23,22,21,20,19,18,17,16,15,14,13,12,11,10,9,
   8,7,6,5,4,3,2,1},
  {1,2,3,4,5,6,15,24,33,42,7,16,25,34,43,8,17,26,35,44,9,18,27,36,45,10,19,28,37,46,
   11,20,29,38,47,12,21,30,39,48,13,22,31,40,49,14,23,32,41,50,
   58,52,53,54,55,56,62,60,61,51,57,59}};

constexpr int cOFFS[4][3][2] = {
  {{0,-1},{-1,-1},{-1,0}},
  {{0, 1},{-1, 0},{-1,1}},
  {{0,-1},{ 1,-1},{ 1,0}},
  {{0,-1},{-1,-1},{-1,0}}};

constexpr Sched make_sched() {
  Sched S{};
  int nslot_all = 0;
  for (int d = 0; d < 4; ++d) {
    int pos_of[63] = {};
    for (int p = 0; p < 62; ++p) pos_of[cDIRS[d][p]] = p;
    int nb[62][3] = {}; int nc[62] = {}; int rdcnt[62] = {};
    for (int p = 0; p < 62; ++p) {
      const int e = cDIRS[d][p];
      const int ci = cCOOR[e-1][0], cj = cCOOR[e-1][1];
      for (int o = 0; o < 3; ++o) {
        const int ni = ci + cOFFS[d][o][0], nj = cj + cOFFS[d][o][1];
        int q = 0;
        for (int k2 = 0; k2 < 62; ++k2)
          if (cCOOR[k2][0]==ni && cCOOR[k2][1]==nj) { q = k2+1; break; }
        if (q) { const int qp = pos_of[q];
          if (qp < p) { nb[p][nc[p]] = qp; nc[p] = nc[p]+1; rdcnt[qp] = rdcnt[qp]+1; } }
      }
    }
    int lvl[62] = {};
    for (int p = 0; p < 62; ++p) {
      int m = 0;
      for (int o = 0; o < nc[p]; ++o) if (lvl[nb[p][o]] > m) m = lvl[nb[p][o]];
      lvl[p] = m + 1;
    }
    int ord[62] = {}; int k = 0;
    for (int L = 1; L <= 62; ++L)
      for (int p = 0; p < 62; ++p) if (lvl[p] == L) { ord[k] = p; k = k+1; }
    int slotof[62] = {};
    int rl[20]; int lr[20];
    for (int s = 0; s < 20; ++s) { rl[s] = 0; lr[s] = -1; }
    int nslot = 0, cur_sub = 0;
    int barafter[62] = {};
    int prev_lvl = lvl[ord[0]];
    for (int kk = 0; kk < 62; ++kk) {
      const int p = ord[kk];
      if (lvl[p] != prev_lvl) { barafter[kk-1] = 1; cur_sub = cur_sub+1; prev_lvl = lvl[p]; }
      for (int o = 0; o < nc[p]; ++o) {
        const int s = slotof[nb[p][o]];
        rl[s] = rl[s]-1;
        if (cur_sub > lr[s]) lr[s] = cur_sub;
      }
      int myslot = 31;
      if (rdcnt[p] > 0) {
        int found = -1;
        for (int s = 0; s < nslot; ++s)
          if (rl[s] == 0 && lr[s] < cur_sub) { found = s; break; }
        if (found < 0 && nslot < 19) { found = nslot; nslot = nslot+1; }
        if (found < 0) {
          barafter[kk-1] = 1; cur_sub = cur_sub+1;
          for (int o = 0; o < nc[p]; ++o) {
            const int s = slotof[nb[p][o]];
            if (cur_sub > lr[s]) lr[s] = cur_sub;
          }
          for (int s = 0; s < nslot; ++s)
            if (rl[s] == 0 && lr[s] < cur_sub) { found = s; break; }
        }
        if (found < 0 && nslot < 20) { found = nslot; nslot = nslot+1; }
        if (found < 0) found = 0;
        myslot = found;
        rl[myslot] = rdcnt[p];
        lr[myslot] = -1;
        slotof[p] = myslot;
      }
      S.opi[d][kk] = (unsigned char)p;
      S.v[d][kk] = (unsigned)(cDIRS[d][p]-1)
                 | ((unsigned)myslot << 6)
                 | ((unsigned)nc[p] << 11)
                 | ((unsigned)(nc[p]>0 ? slotof[nb[p][0]] : 0) << 13)
                 | ((unsigned)(nc[p]>1 ? slotof[nb[p][1]] : 0) << 18)
                 | ((unsigned)(nc[p]>2 ? slotof[nb[p][2]] : 0) << 23);
    }
    for (int kk = 0; kk < 62; ++kk) if (barafter[kk]) S.v[d][kk] |= (1u << 28);
    if (nslot > nslot_all) nslot_all = nslot;
  }
  S.nslot = nslot_all;
  return S;
}

constexpr Sched g_sched = make_sched();
static_assert(g_sched.nslot >= 8 && g_sched.nslot <= 20, "slot pressure out of range");
__constant__ Sched c_sched = make_sched();

constexpr int POOL_B    = g_sched.nslot * 4096;
constexpr int SRNN_SMEM = POOL_B + 256;          // + wproj[64] f32

// ---------------------------------------------------------------------------
// SRNN: template<D> fully-unrolled level-batched scan. Baked slot offsets,
// nb counts, barrier placement. x preloaded to registers (bf16-packed, spread
// over the 4 lhi groups), delivered per step via ds_bpermute.
// ---------------------------------------------------------------------------
template <int D, int K>
__device__ __forceinline__ void do_step(
    char* smem, const float* s_wp,
    const bf16x8 (&wf)[2][4], const bf16x8& uwf0, const bf16x8& uwf1,
    float bias0, float bias1,
    const u32 (&xr)[16][3], const int (&bad)[4],
    const u32 (&rdv)[4], const u32 (&wav)[4],
    f32x4& macc0, f32x4& macc1)
{
  constexpr unsigned sv = g_sched.v[D][K];
  constexpr int snew = (int)((sv >> 6) & 31u);
  constexpr int nbc  = (int)((sv >> 11) & 3u);
  constexpr int sl0  = (int)((sv >> 13) & 31u);
  constexpr int sl1  = (int)((sv >> 18) & 31u);
  constexpr int sl2  = (int)((sv >> 23) & 31u);
  constexpr int g    = K & 3;
  constexpr int js   = K >> 2;

  // x fragment via cross-lane pull from owner group (lhi==0 lanes consume;
  // other lanes' values multiply zero rows of uwf)
  u32 r0 = (u32)__builtin_amdgcn_ds_bpermute(bad[g], (int)xr[js][0]);
  u32 r1 = (u32)__builtin_amdgcn_ds_bpermute(bad[g], (int)xr[js][1]);
  u32 r2 = (u32)__builtin_amdgcn_ds_bpermute(bad[g], (int)xr[js][2]);

  f32x4 a0 = {bias0, bias0, bias0, bias0};
  f32x4 a1 = {bias1, bias1, bias1, bias1};

  if constexpr (nbc > 0) {
#pragma unroll
    for (int kc = 0; kc < 4; ++kc) {
      bf16x8 a = *(const bf16x8*)(smem + sl0 * 4096 + rdv[kc]);
      a0 = __builtin_amdgcn_mfma_f32_16x16x32_bf16(a, wf[0][kc], a0, 0, 0, 0);
      a1 = __builtin_amdgcn_mfma_f32_16x16x32_bf16(a, wf[1][kc], a1, 0, 0, 0);
    }
  }
  if constexpr (nbc > 1) {
#pragma unroll
    for (int kc = 0; kc < 4; ++kc) {
      bf16x8 a = *(const bf16x8*)(smem + sl1 * 4096 + rdv[kc]);
      a0 = __builtin_amdgcn_mfma_f32_16x16x32_bf16(a, wf[0][kc], a0, 0, 0, 0);
      a1 = __builtin_amdgcn_mfma_f32_16x16x32_bf16(a, wf[1][kc], a1, 0, 0, 0);
    }
  }
  if constexpr (nbc > 2) {
#pragma unroll
    for (int kc = 0; kc < 4; ++kc) {
      bf16x8 a = *(const bf16x8*)(smem + sl2 * 4096 + rdv[kc]);
      a0 = __builtin_amdgcn_mfma_f32_16x16x32_bf16(a, wf[0][kc], a0, 0, 0, 0);
      a1 = __builtin_amdgcn_mfma_f32_16x16x32_bf16(a, wf[1][kc], a1, 0, 0, 0);
    }
  }
  {
    u32x4 xv; xv[0] = r0; xv[1] = r1; xv[2] = r2; xv[3] = 0;
    bf16x8 xa = __builtin_bit_cast(bf16x8, xv);
    a0 = __builtin_amdgcn_mfma_f32_16x16x32_bf16(xa, uwf0, a0, 0, 0, 0);
    a1 = __builtin_amdgcn_mfma_f32_16x16x32_bf16(xa, uwf1, a1, 0, 0, 0);
  }

  const float wp = s_wp[K];
  float h0[4], h1[4];
#pragma unroll
  for (int r = 0; r < 4; ++r) { h0[r] = fmaxf(a0[r], 0.f); h1[r] = fmaxf(a1[r], 0.f); }
  if constexpr (snew != 31) {
#pragma unroll
    for (int r = 0; r < 4; ++r)
      *(u32*)(smem + snew * 4096 + wav[r]) = cvtpk(h0[r], h1[r]);
  }
#pragma unroll
  for (int r = 0; r < 4; ++r) { macc0[r] += h0[r] * wp; macc1[r] += h1[r] * wp; }

  if constexpr ((sv >> 28) & 1u) __syncthreads();
}

template <int D, int... Ks>
__device__ __forceinline__ void run_steps(
    std::integer_sequence<int, Ks...>,
    char* smem, const float* s_wp,
    const bf16x8 (&wf)[2][4], const bf16x8& uwf0, const bf16x8& uwf1,
    float bias0, float bias1,
    const u32 (&xr)[16][3], const int (&bad)[4],
    const u32 (&rdv)[4], const u32 (&wav)[4],
    f32x4& macc0, f32x4& macc1)
{
  (do_step<D, Ks>(smem, s_wp, wf, uwf0, uwf1, bias0, bias1,
                  xr, bad, rdv, wav, macc0, macc1), ...);
}

template <int D>
__device__ __noinline__ void srnn_body(
    const float* __restrict__ x,  const float* __restrict__ Uw,
    const float* __restrict__ Ub, const float* __restrict__ Ww,
    const float* __restrict__ Wb, const float* __restrict__ spbs,
    const float* __restrict__ Pw, const float* __restrict__ psw,
    float* __restrict__ part, int bx)
{
  extern __shared__ __align__(16) char smem[];
  const int tid  = threadIdx.x;
  const int lane = tid & 63, wid = tid >> 6;
  const int l15  = lane & 15, lhi = lane >> 4;
  const int bb = bx & 15, tp = bx >> 6;
  const int b0 = bb * 8, t0 = tp * 2;

  float* s_wp = (float*)(smem + POOL_B);

  // wproj (schedule order)
  if (tid < 62) {
    const int opi = c_sched.opi[D][tid];
    float acc = 0.f;
    for (int q = 0; q < 16; ++q) acc += Pw[(D * 16 + q) * 62 + opi] * psw[D * 16 + q];
    s_wp[tid] = acc;
  }

  // W B-fragments, k-interleaved (physical q=2i+j <-> logical k=i+16j)
  bf16x8 wf[2][4];
  float bias0, bias1;
#pragma unroll
  for (int nt = 0; nt < 2; ++nt) {
    const int n = wid * 32 + nt * 16 + l15;
    const float* wr = Ww + (size_t)(D * 128 + n) * 128;
#pragma unroll
    for (int kc = 0; kc < 4; ++kc) {
      float4 lo = *(const float4*)(wr + kc * 32 + lhi * 4);
      float4 hi = *(const float4*)(wr + kc * 32 + lhi * 4 + 16);
      wf[nt][kc] = pack8(lo.x, hi.x, lo.y, hi.y, lo.z, hi.z, lo.w, hi.w);
    }
    float bnt = Ub[D * 128 + n] + Wb[D * 128 + n] + spbs[D * 128 + n];
    if (nt == 0) bias0 = bnt; else bias1 = bnt;
  }

  // Uw B-fragments: only lhi==0 lanes carry real k (c=0..4), rest zero.
  float u0a=0,u1a=0,u2a=0,u3a=0,u4a=0, u0b=0,u1b=0,u2b=0,u3b=0,u4b=0;
  if (lhi == 0) {
    const float* ua = Uw + (D * 128 + wid * 32 + l15) * 5;
    const float* ub = Uw + (D * 128 + wid * 32 + 16 + l15) * 5;
    u0a=ua[0]; u1a=ua[1]; u2a=ua[2]; u3a=ua[3]; u4a=ua[4];
    u0b=ub[0]; u1b=ub[1]; u2b=ub[2]; u3b=ub[3]; u4b=ub[4];
  }
  const bf16x8 uwf0 = pack8(u0a,u1a,u2a,u3a,u4a,0.f,0.f,0.f);
  const bf16x8 uwf1 = pack8(u0b,u1b,u2b,u3b,u4b,0.f,0.f,0.f);

  // x preload: lane (l15, lhi=g) owns steps {k : k&3==g}, slot j=k>>2.
  // Packed bf16: [b0b1][b2b3][b4,0]. All loads issued in bulk here.
  const float* xlane = x + (size_t)((b0 + (l15 & 7)) * 16 + (t0 + (l15 >> 3))) * 310;
  u32 xr[16][3];
#pragma unroll
  for (int j = 0; j < 16; ++j) {
    const int e = (int)(c_sched.v[D][j * 4 + lhi] & 63u);
    const float* xp = xlane + e * 5;
    float x0 = xp[0], x1 = xp[1], x2 = xp[2], x3 = xp[3], x4 = xp[4];
    xr[j][0] = cvtpk(x0, x1);
    xr[j][1] = cvtpk(x2, x3);
    xr[j][2] = cvtpk(x4, 0.f);
  }

  // per-lane LDS byte offsets
  const int swz_r = ((l15 & 7) << 4);
  u32 rdv[4], wav[4];
#pragma unroll
  for (int kc = 0; kc < 4; ++kc)
    rdv[kc] = (u32)(l15 * 256 + ((kc * 64 + lhi * 16) ^ swz_r));
  const int wcol = wid * 64 + l15 * 4;
#pragma unroll
  for (int r = 0; r < 4; ++r) {
    const int row = lhi * 4 + r;
    wav[r] = (u32)(row * 256 + (wcol ^ ((row & 7) << 4)));
  }
  int bad[4];
#pragma unroll
  for (int i = 0; i < 4; ++i) bad[i] = (i * 16 + l15) * 4;

  __syncthreads();

  f32x4 macc0 = {0.f,0.f,0.f,0.f}, macc1 = {0.f,0.f,0.f,0.f};
  run_steps<D>(std::make_integer_sequence<int, 62>{},
               smem, s_wp, wf, uwf0, uwf1, bias0, bias1,
               xr, bad, rdv, wav, macc0, macc1);

#pragma unroll
  for (int r = 0; r < 4; ++r) {
    const int row = lhi * 4 + r;
    const int t = t0 + (row >> 3);
    const int brow = b0 + (row & 7);
    const int n0 = wid * 32 + l15;
    float* pp = part + (((size_t)D * 16 + t) * 128 + brow) * 128;
    pp[n0]      = macc0[r];
    pp[n0 + 16] = macc1[r];
  }
}

__global__ __launch_bounds__(256, 2) void srnn_kernel(
    const float* __restrict__ x,  const float* __restrict__ Uw,
    const float* __restrict__ Ub, const float* __restrict__ Ww,
    const float* __restrict__ Wb, const float* __restrict__ spbs,
    const float* __restrict__ Pw, const float* __restrict__ psw,
    float* __restrict__ part)
{
  const int bx = blockIdx.x;
  switch ((bx >> 4) & 3) {
    case 0: srnn_body<0>(x, Uw, Ub, Ww, Wb, spbs, Pw, psw, part, bx); break;
    case 1: srnn_body<1>(x, Uw, Ub, Ww, Wb, spbs, Pw, psw, part, bx); break;
    case 2: srnn_body<2>(x, Uw, Ub, Ww, Wb, spbs, Pw, psw, part, bx); break;
    default: srnn_body<3>(x, Uw, Ub, Ww, Wb, spbs, Pw, psw, part, bx); break;
  }
}

// ---------------------------------------------------------------------------
// Reduce 4 direction-partials + C0 -> ms (bf16). Also zeroes d_out (block 0).
// ---------------------------------------------------------------------------
__global__ __launch_bounds__(256) void reduce_ms_kernel(
    const float* __restrict__ part, const float* __restrict__ Pb,
    const float* __restrict__ psw,  const float* __restrict__ psb,
    u16* __restrict__ msbf, float* __restrict__ out)
{
  const int tid = threadIdx.x;
  if (blockIdx.x == 0 && tid < 128) {
    float3 z = {0.f, 0.f, 0.f};
    *(float3*)(out + tid * 3) = z;
  }
  const int idx = blockIdx.x * 256 + tid;   // 262144 total
  float c0 = psb[0];
  for (int i = 0; i < 64; ++i) c0 += Pb[i] * psw[i];
  float s = c0 + part[idx] + part[262144 + idx] + part[2 * 262144 + idx] + part[3 * 262144 + idx];
  msbf[idx] = f2bf(s);
}

// ---------------------------------------------------------------------------
// TRNN: 16 WGs = 8 b-blocks x 2 dirs. ms read from bf16 msbf (L2-warm) into
// swizzled LDS; in-register p1-dot reduction; atomicAdd into pre-zeroed out.
// ---------------------------------------------------------------------------
constexpr int MS_OFF = 0;                 // [16 t][16 b][256 B] swizzled bf16
constexpr int HB_OFF = 65536;             // hbuf [2][16][136] u16 = 8704
constexpr int SW_OFF = HB_OFF + 8704;     // sredw [16][16][4] f32 = 4096
constexpr int S2_OFF = SW_OFF + 4096;     // sred2 [16][16] f32 = 1024
constexpr int TRNN_SMEM = S2_OFF + 1024;  // 79360

__global__ __launch_bounds__(256) void trnn_kernel(
    const u16* __restrict__ msbf,
    const float* __restrict__ frs, const float* __restrict__ frsb,
    const float* __restrict__ fvs, const float* __restrict__ fvsb,
    const float* __restrict__ fbs, const float* __restrict__ fpj, const float* __restrict__ fpjb,
    const float* __restrict__ brs, const float* __restrict__ brsb,
    const float* __restrict__ bvs, const float* __restrict__ bvsb,
    const float* __restrict__ bbs, const float* __restrict__ bpj, const float* __restrict__ bpjb,
    const float* __restrict__ fp1w, const float* __restrict__ fp1b,
    const float* __restrict__ fp2w, const float* __restrict__ fp2b,
    const float* __restrict__ bp1w, const float* __restrict__ bp1b,
    const float* __restrict__ bp2w, const float* __restrict__ bp2b,
    float* __restrict__ out)
{
  extern __shared__ __align__(16) char smem[];
  const int tid = threadIdx.x;
  const int lane = tid & 63, wid = tid >> 6;
  const int l15 = lane & 15, lhi = lane >> 4;
  const int dir = blockIdx.x & 1;
  const int b0 = (blockIdx.x >> 1) * 16;

  const float* rs  = dir ? brs  : frs;
  const float* rsb = dir ? brsb : frsb;
  const float* vs  = dir ? bvs  : fvs;
  const float* vsb = dir ? bvsb : fvsb;
  const float* bs  = dir ? bbs  : fbs;
  const float* w1  = dir ? bp1w : fp1w;

  // ---- prologue A: ms slice (bf16) -> LDS swizzled ---------------------------
  {
    const int tq = tid >> 4, bq = tid & 15;
    const u16* mg = msbf + ((size_t)tq * 128 + b0 + bq) * 128;
    char* mrow = smem + MS_OFF + (tq * 16 + bq) * 256;
    const int sz = (bq & 7) << 4;
#pragma unroll
    for (int q = 0; q < 16; ++q) {
      uint4 v = *(const uint4*)(mg + q * 8);
      *(u32*)(mrow + ((q * 16)      ^ sz)) = v.x;
      *(u32*)(mrow + ((q * 16 + 4)  ^ sz)) = v.y;
      *(u32*)(mrow + ((q * 16 + 8)  ^ sz)) = v.z;
      *(u32*)(mrow + ((q * 16 + 12) ^ sz)) = v.w;
    }
  }

  // ---- prologue B: weight fragments ------------------------------------------
  bf16x8 rf[2][4], vf[2][4];
  float bias[2], w1a, w1b;
#pragma unroll
  for (int nt = 0; nt < 2; ++nt) {
    const int n = wid * 32 + nt * 16 + l15;
#pragma unroll
    for (int kc = 0; kc < 4; ++kc) {
      float4 ra = *(const float4*)(rs + (size_t)n * 128 + kc * 32 + lhi * 8);
      float4 rb = *(const float4*)(rs + (size_t)n * 128 + kc * 32 + lhi * 8 + 4);
      rf[nt][kc] = pack8(ra.x, ra.y, ra.z, ra.w, rb.x, rb.y, rb.z, rb.w);
      float4 lo = *(const float4*)(vs + (size_t)n * 128 + kc * 32 + lhi * 4);
      float4 hi = *(const float4*)(vs + (size_t)n * 128 + kc * 32 + lhi * 4 + 16);
      vf[nt][kc] = pack8(lo.x, hi.x, lo.y, hi.y, lo.z, hi.z, lo.w, hi.w);
    }
    bias[nt] = rsb[n] + vsb[n] + bs[n];
  }
  w1a = w1[wid * 32 + l15];
  w1b = w1[wid * 32 + 16 + l15];

  for (int i = tid; i < 2176; i += 256) *(u16*)(smem + HB_OFF + i * 2) = 0;
  __syncthreads();

  float* sredw = (float*)(smem + SW_OFF);
  float* sred2 = (float*)(smem + S2_OFF);

  int cur = 0;
  for (int tt2 = 0; tt2 < 16; ++tt2) {
    const int tt = dir ? (15 - tt2) : tt2;
    f32x4 am0 = {bias[0],bias[0],bias[0],bias[0]};
    f32x4 am1 = {bias[1],bias[1],bias[1],bias[1]};
    f32x4 ah0 = {0.f,0.f,0.f,0.f}, ah1 = {0.f,0.f,0.f,0.f};
    const char* msrow = smem + MS_OFF + (tt * 16 + l15) * 256;
    const int msz = (l15 & 7) << 4;
#pragma unroll
    for (int kc = 0; kc < 4; ++kc) {
      bf16x8 ma = *(const bf16x8*)(msrow + ((kc * 64 + lhi * 16) ^ msz));
      bf16x8 ha = *(const bf16x8*)(smem + HB_OFF + (cur * 16 + l15) * 272 + kc * 64 + lhi * 16);
      am0 = __builtin_amdgcn_mfma_f32_16x16x32_bf16(ma, rf[0][kc], am0, 0, 0, 0);
      ah0 = __builtin_amdgcn_mfma_f32_16x16x32_bf16(ha, vf[0][kc], ah0, 0, 0, 0);
      am1 = __builtin_amdgcn_mfma_f32_16x16x32_bf16(ma, rf[1][kc], am1, 0, 0, 0);
      ah1 = __builtin_amdgcn_mfma_f32_16x16x32_bf16(ha, vf[1][kc], ah1, 0, 0, 0);
    }
    float pr[4];
#pragma unroll
    for (int r = 0; r < 4; ++r) {
      const int row = lhi * 4 + r;
      float h0 = fmaxf(am0[r] + ah0[r], 0.f);
      float h1 = fmaxf(am1[r] + ah1[r], 0.f);
      *(u32*)(smem + HB_OFF + ((cur ^ 1) * 16 + row) * 272 + wid * 64 + l15 * 4) = cvtpk(h0, h1);
      pr[r] = h0 * w1a + h1 * w1b;
    }
#pragma unroll
    for (int r = 0; r < 4; ++r) {
      float p = pr[r];
      p += __shfl_xor(p, 1);
      p += __shfl_xor(p, 2);
      p += __shfl_xor(p, 4);
      p += __shfl_xor(p, 8);
      if (l15 == 0) sredw[(tt2 * 16 + lhi * 4 + r) * 4 + wid] = p;
    }
    __syncthreads();
    cur ^= 1;
  }

  {
    const int tq = tid >> 4, bq = tid & 15;
    const float* sw = sredw + (tq * 16 + bq) * 4;
    sred2[tq * 16 + bq] = sw[0] + sw[1] + sw[2] + sw[3];
  }
  __syncthreads();

  if (tid < 48) {
    const int b = tid / 3, c = tid % 3;
    const float* p1w = dir ? bp1w : fp1w;
    const float* p1b = dir ? bp1b : fp1b;
    const float* p2w = dir ? bp2w : fp2w;
    const float* p2b = dir ? bp2b : fp2b;
    const float* pj  = dir ? bpj  : fpj;
    const float* pjb = dir ? bpjb : fpjb;
    float S1 = 0.f;
    for (int h = 0; h < 128; ++h) S1 += p1w[h];
    float val = p2b[c];
    for (int p = 0; p < 8; ++p) val += (pjb[p] * S1 + p1b[0]) * p2w[c * 8 + p];
    for (int t2 = 0; t2 < 16; ++t2) {
      float g = 0.f;
      for (int p = 0; p < 8; ++p) g += p2w[c * 8 + p] * pj[p * 16 + t2];
      val += sred2[t2 * 16 + b] * g;
    }
    atomicAdd(out + (b0 + b) * 3 + c, val);
  }
}

extern "C" void kernel_launch(void* const* d_in, const int* in_sizes, int n_in,
                              void* d_out, int out_size, void* d_ws, size_t ws_size,
                              hipStream_t stream)
{
  (void)in_sizes; (void)n_in; (void)out_size; (void)ws_size;
  const float* x    = (const float*)d_in[0];
  const float* Uw   = (const float*)d_in[3];
  const float* Ub   = (const float*)d_in[4];
  const float* Ww   = (const float*)d_in[5];
  const float* Wb   = (const float*)d_in[6];
  const float* spbs = (const float*)d_in[7];
  const float* Pw   = (const float*)d_in[8];
  const float* Pb   = (const float*)d_in[9];
  const float* psw  = (const float*)d_in[10];
  const float* psb  = (const float*)d_in[11];
  const float* frs  = (const float*)d_in[12];
  const float* frsb = (const float*)d_in[13];
  const float* fvs  = (const float*)d_in[14];
  const float* fvsb = (const float*)d_in[15];
  const float* fbs  = (const float*)d_in[16];
  const float* fpj  = (const float*)d_in[17];
  const float* fpjb = (const float*)d_in[18];
  const float* brs  = (const float*)d_in[19];
  const float* brsb = (const float*)d_in[20];
  const float* bvs  = (const float*)d_in[21];
  const float* bvsb = (const float*)d_in[22];
  const float* bbs  = (const float*)d_in[23];
  const float* bpj  = (const float*)d_in[24];
  const float* bpjb = (const float*)d_in[25];
  const float* fp1w = (const float*)d_in[26];
  const float* fp1b = (const float*)d_in[27];
  const float* fp2w = (const float*)d_in[28];
  const float* fp2b = (const float*)d_in[29];
  const float* bp1w = (const float*)d_in[30];
  const float* bp1b = (const float*)d_in[31];
  const float* bp2w = (const float*)d_in[32];
  const float* bp2b = (const float*)d_in[33];

  char* ws = (char*)d_ws;
  float* part = (float*)ws;                 // 4 MiB [4][16][128][128] f32
  u16*   msbf = (u16*)(ws + 4194304);       // 512 KiB [16][128][128] bf16

  hipFuncSetAttribute((const void*)srnn_kernel,
                      hipFuncAttributeMaxDynamicSharedMemorySize, SRNN_SMEM);
  hipFuncSetAttribute((const void*)trnn_kernel,
                      hipFuncAttributeMaxDynamicSharedMemorySize, TRNN_SMEM);

  srnn_kernel<<<dim3(512), dim3(256), SRNN_SMEM, stream>>>(
      x, Uw, Ub, Ww, Wb, spbs, Pw, psw, part);
  reduce_ms_kernel<<<dim3(1024), dim3(256), 0, stream>>>(
      part, Pb, psw, psb, msbf, (float*)d_out);
  trnn_kernel<<<dim3(16), dim3(256), TRNN_SMEM, stream>>>(msbf,
      frs, frsb, fvs, fvsb, fbs, fpj, fpjb,
      brs, brsb, bvs, bvsb, bbs, bpj, bpjb,
      fp1w, fp1b, fp2w, fp2b, bp1w, bp1b, bp2w, bp2b,
      (float*)d_out);
}